// Round 1
// baseline (4995.352 us; speedup 1.0000x reference)
//
#include <hip/hip_runtime.h>
#include <math.h>

#define N_NODES 40000
#define N_EDGES 640000
#define D 128

__device__ __forceinline__ float silu(float x) { return x / (1.0f + __expf(-x)); }

// ---------------------------------------------------------------------------
// k_pre: P1 = nf @ We1[0:128,:], P2 = nf @ We1[128:256,:]
// block = 256 threads, 32 nodes per block. thread t -> output col jj=t&127,
// half = t>>7 selects P1/P2. acc[32] over the node tile; nf tile in LDS
// (broadcast reads), We1 streamed from global (L2-hot, 128 KB total).
// ---------------------------------------------------------------------------
__global__ __launch_bounds__(256) void k_pre(const float* __restrict__ nf,
                                             const float* __restrict__ We1,
                                             float* __restrict__ P1,
                                             float* __restrict__ P2) {
    __shared__ float sA[32][128];
    const int t = threadIdx.x;
    const int node0 = blockIdx.x * 32;
    {
        const int m = t >> 3, c = (t & 7) * 16;
        const float4* sp = (const float4*)&nf[(size_t)(node0 + m) * 128 + c];
        float4* dp = (float4*)&sA[m][c];
        dp[0] = sp[0]; dp[1] = sp[1]; dp[2] = sp[2]; dp[3] = sp[3];
    }
    __syncthreads();

    const int jj = t & 127;
    const int half = t >> 7;
    const float* W = We1 + (size_t)half * 128 * 128 + jj;

    float acc[32];
#pragma unroll
    for (int m = 0; m < 32; m++) acc[m] = 0.0f;

    for (int k = 0; k < 128; k += 4) {
        const float w0 = W[(size_t)(k + 0) * 128];
        const float w1 = W[(size_t)(k + 1) * 128];
        const float w2 = W[(size_t)(k + 2) * 128];
        const float w3 = W[(size_t)(k + 3) * 128];
#pragma unroll
        for (int m = 0; m < 32; m++) {
            const float4 a = *(const float4*)&sA[m][k];
            acc[m] += a.x * w0 + a.y * w1 + a.z * w2 + a.w * w3;
        }
    }
    float* P = half ? P2 : P1;
#pragma unroll
    for (int m = 0; m < 32; m++) P[(size_t)(node0 + m) * 128 + jj] = acc[m];
}

// ---------------------------------------------------------------------------
// k_edge: per 32-edge tile:
//   t1 = silu(P1[src] + P2[dst] + dist*We1[256] + be1)     (LDS)
//   t2 = silu(t1 @ We2 + be2)                              (LDS) -> atomic h
//   coef = silu(t2 @ Wc1 + bc1) . Wc2                      -> atomic x,cnt
// GEMM micro-tile: thread = 2 cols x 8 edges; weights streamed from L2.
// ---------------------------------------------------------------------------
__global__ __launch_bounds__(256) void k_edge(
    const float* __restrict__ P1, const float* __restrict__ P2,
    const float* __restrict__ coord,
    const int* __restrict__ src, const int* __restrict__ dst,
    const float* __restrict__ We1, const float* __restrict__ be1,
    const float* __restrict__ We2, const float* __restrict__ be2,
    const float* __restrict__ Wc1, const float* __restrict__ bc1,
    const float* __restrict__ Wc2,
    float* __restrict__ h_neigh, float* __restrict__ x_cnt) {
    __shared__ float sT1[32][128];
    __shared__ float sT2[32][128];
    __shared__ float sdist[32];
    __shared__ float sxd[32][3];
    __shared__ int ssrc[32];
    __shared__ int sdst[32];
    __shared__ float scoef[32];

    const int t = threadIdx.x;
    const int e0 = blockIdx.x * 32;

    if (t < 32) {
        const int e = e0 + t;
        const int s = src[e], d = dst[e];
        ssrc[t] = s; sdst[t] = d;
        const float dx = coord[3 * s + 0] - coord[3 * d + 0];
        const float dy = coord[3 * s + 1] - coord[3 * d + 1];
        const float dz = coord[3 * s + 2] - coord[3 * d + 2];
        const float dist = sqrtf(dx * dx + dy * dy + dz * dz);
        sdist[t] = dist;
        const float inv = 1.0f / (dist + 1e-7f);
        sxd[t][0] = dx * inv; sxd[t][1] = dy * inv; sxd[t][2] = dz * inv;
    }
    __syncthreads();

    const int e = t >> 3;
    const int k0 = (t & 7) * 16;
    {
        const int s = ssrc[e], d = sdst[e];
        const float dist = sdist[e];
#pragma unroll
        for (int kk = 0; kk < 16; kk += 4) {
            const int k = k0 + kk;
            const float4 a = *(const float4*)&P1[(size_t)s * 128 + k];
            const float4 b = *(const float4*)&P2[(size_t)d * 128 + k];
            const float4 w = *(const float4*)&We1[256 * 128 + k];
            const float4 bb = *(const float4*)&be1[k];
            float4 v;
            v.x = silu(a.x + b.x + dist * w.x + bb.x);
            v.y = silu(a.y + b.y + dist * w.y + bb.y);
            v.z = silu(a.z + b.z + dist * w.z + bb.z);
            v.w = silu(a.w + b.w + dist * w.w + bb.w);
            *(float4*)&sT1[e][k] = v;
        }
    }
    __syncthreads();

    const int jj = (t & 63) * 2;
    const int eb = (t >> 6) * 8;

    // GEMM1: t2 = silu(t1 @ We2 + be2)
    {
        float acc0[8], acc1[8];
#pragma unroll
        for (int i = 0; i < 8; i++) { acc0[i] = 0.0f; acc1[i] = 0.0f; }
        for (int k = 0; k < 128; k += 4) {
            const float2 w0 = *(const float2*)&We2[(size_t)(k + 0) * 128 + jj];
            const float2 w1 = *(const float2*)&We2[(size_t)(k + 1) * 128 + jj];
            const float2 w2 = *(const float2*)&We2[(size_t)(k + 2) * 128 + jj];
            const float2 w3 = *(const float2*)&We2[(size_t)(k + 3) * 128 + jj];
#pragma unroll
            for (int i = 0; i < 8; i++) {
                const float4 a = *(const float4*)&sT1[eb + i][k];
                acc0[i] += a.x * w0.x + a.y * w1.x + a.z * w2.x + a.w * w3.x;
                acc1[i] += a.x * w0.y + a.y * w1.y + a.z * w2.y + a.w * w3.y;
            }
        }
        const float2 b2 = *(const float2*)&be2[jj];
#pragma unroll
        for (int i = 0; i < 8; i++) {
            float2 v;
            v.x = silu(acc0[i] + b2.x);
            v.y = silu(acc1[i] + b2.y);
            *(float2*)&sT2[eb + i][jj] = v;
        }
    }
    __syncthreads();

    // GEMM2: coef = silu(t2 @ Wc1 + bc1) . Wc2
    {
        float acc0[8], acc1[8];
#pragma unroll
        for (int i = 0; i < 8; i++) { acc0[i] = 0.0f; acc1[i] = 0.0f; }
        for (int k = 0; k < 128; k += 4) {
            const float2 w0 = *(const float2*)&Wc1[(size_t)(k + 0) * 128 + jj];
            const float2 w1 = *(const float2*)&Wc1[(size_t)(k + 1) * 128 + jj];
            const float2 w2 = *(const float2*)&Wc1[(size_t)(k + 2) * 128 + jj];
            const float2 w3 = *(const float2*)&Wc1[(size_t)(k + 3) * 128 + jj];
#pragma unroll
            for (int i = 0; i < 8; i++) {
                const float4 a = *(const float4*)&sT2[eb + i][k];
                acc0[i] += a.x * w0.x + a.y * w1.x + a.z * w2.x + a.w * w3.x;
                acc1[i] += a.x * w0.y + a.y * w1.y + a.z * w2.y + a.w * w3.y;
            }
        }
        const float2 bc = *(const float2*)&bc1[jj];
        const float2 wc = *(const float2*)&Wc2[jj];
        float part[8];
#pragma unroll
        for (int i = 0; i < 8; i++)
            part[i] = silu(acc0[i] + bc.x) * wc.x + silu(acc1[i] + bc.y) * wc.y;
#pragma unroll
        for (int off = 32; off >= 1; off >>= 1) {
#pragma unroll
            for (int i = 0; i < 8; i++) part[i] += __shfl_xor(part[i], off, 64);
        }
        const int lane = t & 63;
        if (lane < 8) scoef[eb + lane] = part[lane];
    }
    __syncthreads();

    // scatter x / cnt
    if (t < 32) {
        const float coef = scoef[t];
        const int d = sdst[t];
        atomicAdd(&x_cnt[(size_t)d * 4 + 0], coef * sxd[t][0]);
        atomicAdd(&x_cnt[(size_t)d * 4 + 1], coef * sxd[t][1]);
        atomicAdd(&x_cnt[(size_t)d * 4 + 2], coef * sxd[t][2]);
        atomicAdd(&x_cnt[(size_t)d * 4 + 3], 1.0f);
    }
    // scatter h (same e/k0 mapping as the staging phase)
    {
        const int d = sdst[e];
#pragma unroll
        for (int kk = 0; kk < 16; kk++)
            atomicAdd(&h_neigh[(size_t)d * 128 + k0 + kk], sT2[e][k0 + kk]);
    }
}

// ---------------------------------------------------------------------------
// k_node: h = silu(nf@Wn1a + hn@Wn1b + bn1) @ Wn2 + bn2 ; x = coord + xs/cnt
// ---------------------------------------------------------------------------
__global__ __launch_bounds__(256) void k_node(
    const float* __restrict__ nf, const float* __restrict__ coord,
    const float* __restrict__ hn, const float* __restrict__ xc,
    const float* __restrict__ Wn1, const float* __restrict__ bn1,
    const float* __restrict__ Wn2, const float* __restrict__ bn2,
    float* __restrict__ out_h, float* __restrict__ out_x) {
    __shared__ float sA[32][128];
    __shared__ float sB[32][128];
    const int t = threadIdx.x;
    const int node0 = blockIdx.x * 32;
    {
        const int m = t >> 3, c = (t & 7) * 16;
        const float4* sp = (const float4*)&nf[(size_t)(node0 + m) * 128 + c];
        float4* dp = (float4*)&sA[m][c];
        dp[0] = sp[0]; dp[1] = sp[1]; dp[2] = sp[2]; dp[3] = sp[3];
        const float4* sp2 = (const float4*)&hn[(size_t)(node0 + m) * 128 + c];
        float4* dp2 = (float4*)&sB[m][c];
        dp2[0] = sp2[0]; dp2[1] = sp2[1]; dp2[2] = sp2[2]; dp2[3] = sp2[3];
    }
    // coord output (independent of the MLP)
    if (t < 96) {
        const int m = t / 3, c = t - m * 3;
        const int i = node0 + m;
        const float cnt = xc[(size_t)i * 4 + 3];
        out_x[(size_t)i * 3 + c] =
            coord[(size_t)i * 3 + c] + xc[(size_t)i * 4 + c] / fmaxf(cnt, 1.0f);
    }
    __syncthreads();

    const int jj = (t & 63) * 2;
    const int mb = (t >> 6) * 8;

    float acc0[8], acc1[8];
#pragma unroll
    for (int i = 0; i < 8; i++) { acc0[i] = 0.0f; acc1[i] = 0.0f; }
    for (int k = 0; k < 128; k += 4) {  // nf part: Wn1 rows 0..127
        const float2 w0 = *(const float2*)&Wn1[(size_t)(k + 0) * 128 + jj];
        const float2 w1 = *(const float2*)&Wn1[(size_t)(k + 1) * 128 + jj];
        const float2 w2 = *(const float2*)&Wn1[(size_t)(k + 2) * 128 + jj];
        const float2 w3 = *(const float2*)&Wn1[(size_t)(k + 3) * 128 + jj];
#pragma unroll
        for (int i = 0; i < 8; i++) {
            const float4 a = *(const float4*)&sA[mb + i][k];
            acc0[i] += a.x * w0.x + a.y * w1.x + a.z * w2.x + a.w * w3.x;
            acc1[i] += a.x * w0.y + a.y * w1.y + a.z * w2.y + a.w * w3.y;
        }
    }
    for (int k = 0; k < 128; k += 4) {  // h_neigh part: Wn1 rows 128..255
        const float2 w0 = *(const float2*)&Wn1[(size_t)(128 + k + 0) * 128 + jj];
        const float2 w1 = *(const float2*)&Wn1[(size_t)(128 + k + 1) * 128 + jj];
        const float2 w2 = *(const float2*)&Wn1[(size_t)(128 + k + 2) * 128 + jj];
        const float2 w3 = *(const float2*)&Wn1[(size_t)(128 + k + 3) * 128 + jj];
#pragma unroll
        for (int i = 0; i < 8; i++) {
            const float4 a = *(const float4*)&sB[mb + i][k];
            acc0[i] += a.x * w0.x + a.y * w1.x + a.z * w2.x + a.w * w3.x;
            acc1[i] += a.x * w0.y + a.y * w1.y + a.z * w2.y + a.w * w3.y;
        }
    }
    const float2 b1 = *(const float2*)&bn1[jj];
    __syncthreads();
#pragma unroll
    for (int i = 0; i < 8; i++) {
        float2 v;
        v.x = silu(acc0[i] + b1.x);
        v.y = silu(acc1[i] + b1.y);
        *(float2*)&sA[mb + i][jj] = v;
    }
    __syncthreads();

#pragma unroll
    for (int i = 0; i < 8; i++) { acc0[i] = 0.0f; acc1[i] = 0.0f; }
    for (int k = 0; k < 128; k += 4) {
        const float2 w0 = *(const float2*)&Wn2[(size_t)(k + 0) * 128 + jj];
        const float2 w1 = *(const float2*)&Wn2[(size_t)(k + 1) * 128 + jj];
        const float2 w2 = *(const float2*)&Wn2[(size_t)(k + 2) * 128 + jj];
        const float2 w3 = *(const float2*)&Wn2[(size_t)(k + 3) * 128 + jj];
#pragma unroll
        for (int i = 0; i < 8; i++) {
            const float4 a = *(const float4*)&sA[mb + i][k];
            acc0[i] += a.x * w0.x + a.y * w1.x + a.z * w2.x + a.w * w3.x;
            acc1[i] += a.x * w0.y + a.y * w1.y + a.z * w2.y + a.w * w3.y;
        }
    }
    const float2 b2 = *(const float2*)&bn2[jj];
#pragma unroll
    for (int i = 0; i < 8; i++) {
        float2 v;
        v.x = acc0[i] + b2.x;
        v.y = acc1[i] + b2.y;
        *(float2*)&out_h[(size_t)(node0 + mb + i) * 128 + jj] = v;
    }
}

// ---------------------------------------------------------------------------
extern "C" void kernel_launch(void* const* d_in, const int* in_sizes, int n_in,
                              void* d_out, int out_size, void* d_ws, size_t ws_size,
                              hipStream_t stream) {
    const float* nf    = (const float*)d_in[0];
    const float* coord = (const float*)d_in[1];
    const int*   src   = (const int*)d_in[2];
    const int*   dst   = (const int*)d_in[3];
    const float* We1   = (const float*)d_in[4];
    const float* be1   = (const float*)d_in[5];
    const float* We2   = (const float*)d_in[6];
    const float* be2   = (const float*)d_in[7];
    const float* Wn1   = (const float*)d_in[8];
    const float* bn1   = (const float*)d_in[9];
    const float* Wn2   = (const float*)d_in[10];
    const float* bn2   = (const float*)d_in[11];
    const float* Wc1   = (const float*)d_in[12];
    const float* bc1   = (const float*)d_in[13];
    const float* Wc2   = (const float*)d_in[14];

    float* P1 = (float*)d_ws;                         // N*128
    float* P2 = P1 + (size_t)N_NODES * 128;           // N*128
    float* hn = P2 + (size_t)N_NODES * 128;           // N*128
    float* xc = hn + (size_t)N_NODES * 128;           // N*4 (xsum.xyz, cnt)

    float* out_h = (float*)d_out;                     // N*128
    float* out_x = out_h + (size_t)N_NODES * 128;     // N*3

    hipMemsetAsync(hn, 0, (size_t)N_NODES * 128 * sizeof(float), stream);
    hipMemsetAsync(xc, 0, (size_t)N_NODES * 4 * sizeof(float), stream);

    k_pre<<<N_NODES / 32, 256, 0, stream>>>(nf, We1, P1, P2);
    k_edge<<<N_EDGES / 32, 256, 0, stream>>>(P1, P2, coord, src, dst, We1, be1,
                                             We2, be2, Wc1, bc1, Wc2, hn, xc);
    k_node<<<N_NODES / 32, 256, 0, stream>>>(nf, coord, hn, xc, Wn1, bn1, Wn2,
                                             bn2, out_h, out_x);
}

// Round 2
// 1235.384 us; speedup vs baseline: 4.0436x; 4.0436x over previous
//
#include <hip/hip_runtime.h>
#include <math.h>

#define N_NODES 40000
#define N_EDGES 640000
#define D 128

__device__ __forceinline__ float silu(float x) { return x / (1.0f + __expf(-x)); }

// ---------------------------------------------------------------------------
// CSR build: deg histogram -> exclusive scan -> fill permuted edge list.
// ---------------------------------------------------------------------------
__global__ __launch_bounds__(256) void k_count(const int* __restrict__ dst,
                                               int* __restrict__ deg) {
    const int e = blockIdx.x * 256 + threadIdx.x;
    if (e < N_EDGES) atomicAdd(&deg[dst[e]], 1);
}

__global__ __launch_bounds__(1024) void k_scan(const int* __restrict__ deg,
                                               int* __restrict__ row_start) {
    __shared__ int tmp[1024];
    __shared__ int base;
    const int t = threadIdx.x;
    if (t == 0) { base = 0; row_start[0] = 0; }
    __syncthreads();
    for (int off = 0; off < N_NODES; off += 1024) {
        int v = (off + t < N_NODES) ? deg[off + t] : 0;
        tmp[t] = v;
        __syncthreads();
        for (int s = 1; s < 1024; s <<= 1) {
            int u = (t >= s) ? tmp[t - s] : 0;
            __syncthreads();
            tmp[t] += u;
            __syncthreads();
        }
        const int b = base;
        if (off + t < N_NODES) row_start[off + t + 1] = b + tmp[t];
        __syncthreads();
        if (t == 0) base += tmp[1023];
        __syncthreads();
    }
}

__global__ __launch_bounds__(256) void k_fill(const int* __restrict__ dst,
                                              const int* __restrict__ row_start,
                                              int* __restrict__ cursor,
                                              int* __restrict__ elist) {
    const int e = blockIdx.x * 256 + threadIdx.x;
    if (e < N_EDGES) {
        const int d = dst[e];
        const int p = atomicAdd(&cursor[d], 1);
        elist[row_start[d] + p] = e;
    }
}

// ---------------------------------------------------------------------------
// k_pre: P1 = nf @ We1[0:128,:], P2 = nf @ We1[128:256,:]
// ---------------------------------------------------------------------------
__global__ __launch_bounds__(256) void k_pre(const float* __restrict__ nf,
                                             const float* __restrict__ We1,
                                             float* __restrict__ P1,
                                             float* __restrict__ P2) {
    __shared__ float sA[32][128];
    const int t = threadIdx.x;
    const int node0 = blockIdx.x * 32;
    {
        const int m = t >> 3, c = (t & 7) * 16;
        const float4* sp = (const float4*)&nf[(size_t)(node0 + m) * 128 + c];
        float4* dp = (float4*)&sA[m][c];
        dp[0] = sp[0]; dp[1] = sp[1]; dp[2] = sp[2]; dp[3] = sp[3];
    }
    __syncthreads();

    const int jj = t & 127;
    const int half = t >> 7;
    const float* W = We1 + (size_t)half * 128 * 128 + jj;

    float acc[32];
#pragma unroll
    for (int m = 0; m < 32; m++) acc[m] = 0.0f;

    for (int k = 0; k < 128; k += 4) {
        const float w0 = W[(size_t)(k + 0) * 128];
        const float w1 = W[(size_t)(k + 1) * 128];
        const float w2 = W[(size_t)(k + 2) * 128];
        const float w3 = W[(size_t)(k + 3) * 128];
#pragma unroll
        for (int m = 0; m < 32; m++) {
            const float4 a = *(const float4*)&sA[m][k];
            acc[m] += a.x * w0 + a.y * w1 + a.z * w2 + a.w * w3;
        }
    }
    float* P = half ? P2 : P1;
#pragma unroll
    for (int m = 0; m < 32; m++) P[(size_t)(node0 + m) * 128 + jj] = acc[m];
}

// ---------------------------------------------------------------------------
// k_edge2: processes 32 CSR-permuted edges (grouped by dst). Segment-reduces
// h and x contributions in LDS; ~3 atomic row-flushes per block instead of 32.
// ---------------------------------------------------------------------------
__global__ __launch_bounds__(256) void k_edge2(
    const float* __restrict__ P1, const float* __restrict__ P2,
    const float* __restrict__ coord,
    const int* __restrict__ src, const int* __restrict__ dst,
    const int* __restrict__ elist,
    const float* __restrict__ We1, const float* __restrict__ be1,
    const float* __restrict__ We2, const float* __restrict__ be2,
    const float* __restrict__ Wc1, const float* __restrict__ bc1,
    const float* __restrict__ Wc2,
    float* __restrict__ h_neigh, float* __restrict__ xs) {
    __shared__ float sT1[32][128];
    __shared__ float sT2[32][128];
    __shared__ float sdist[32];
    __shared__ float sxd[32][3];
    __shared__ int ssrc[32];
    __shared__ int sdst[32];
    __shared__ float scoef[32];

    const int t = threadIdx.x;
    const int e0 = blockIdx.x * 32;

    if (t < 32) {
        const int eid = elist[e0 + t];
        const int s = src[eid], d = dst[eid];
        ssrc[t] = s; sdst[t] = d;
        const float dx = coord[3 * s + 0] - coord[3 * d + 0];
        const float dy = coord[3 * s + 1] - coord[3 * d + 1];
        const float dz = coord[3 * s + 2] - coord[3 * d + 2];
        const float dist = sqrtf(dx * dx + dy * dy + dz * dz);
        sdist[t] = dist;
        const float inv = 1.0f / (dist + 1e-7f);
        sxd[t][0] = dx * inv; sxd[t][1] = dy * inv; sxd[t][2] = dz * inv;
    }
    __syncthreads();

    const int e = t >> 3;
    const int k0 = (t & 7) * 16;
    {
        const int s = ssrc[e], d = sdst[e];
        const float dist = sdist[e];
#pragma unroll
        for (int kk = 0; kk < 16; kk += 4) {
            const int k = k0 + kk;
            const float4 a = *(const float4*)&P1[(size_t)s * 128 + k];
            const float4 b = *(const float4*)&P2[(size_t)d * 128 + k];
            const float4 w = *(const float4*)&We1[256 * 128 + k];
            const float4 bb = *(const float4*)&be1[k];
            float4 v;
            v.x = silu(a.x + b.x + dist * w.x + bb.x);
            v.y = silu(a.y + b.y + dist * w.y + bb.y);
            v.z = silu(a.z + b.z + dist * w.z + bb.z);
            v.w = silu(a.w + b.w + dist * w.w + bb.w);
            *(float4*)&sT1[e][k] = v;
        }
    }
    __syncthreads();

    const int jj = (t & 63) * 2;
    const int eb = (t >> 6) * 8;

    // GEMM1: t2 = silu(t1 @ We2 + be2)
    {
        float acc0[8], acc1[8];
#pragma unroll
        for (int i = 0; i < 8; i++) { acc0[i] = 0.0f; acc1[i] = 0.0f; }
        for (int k = 0; k < 128; k += 4) {
            const float2 w0 = *(const float2*)&We2[(size_t)(k + 0) * 128 + jj];
            const float2 w1 = *(const float2*)&We2[(size_t)(k + 1) * 128 + jj];
            const float2 w2 = *(const float2*)&We2[(size_t)(k + 2) * 128 + jj];
            const float2 w3 = *(const float2*)&We2[(size_t)(k + 3) * 128 + jj];
#pragma unroll
            for (int i = 0; i < 8; i++) {
                const float4 a = *(const float4*)&sT1[eb + i][k];
                acc0[i] += a.x * w0.x + a.y * w1.x + a.z * w2.x + a.w * w3.x;
                acc1[i] += a.x * w0.y + a.y * w1.y + a.z * w2.y + a.w * w3.y;
            }
        }
        const float2 b2 = *(const float2*)&be2[jj];
#pragma unroll
        for (int i = 0; i < 8; i++) {
            float2 v;
            v.x = silu(acc0[i] + b2.x);
            v.y = silu(acc1[i] + b2.y);
            *(float2*)&sT2[eb + i][jj] = v;
        }
    }
    __syncthreads();

    // GEMM2: coef = silu(t2 @ Wc1 + bc1) . Wc2
    {
        float acc0[8], acc1[8];
#pragma unroll
        for (int i = 0; i < 8; i++) { acc0[i] = 0.0f; acc1[i] = 0.0f; }
        for (int k = 0; k < 128; k += 4) {
            const float2 w0 = *(const float2*)&Wc1[(size_t)(k + 0) * 128 + jj];
            const float2 w1 = *(const float2*)&Wc1[(size_t)(k + 1) * 128 + jj];
            const float2 w2 = *(const float2*)&Wc1[(size_t)(k + 2) * 128 + jj];
            const float2 w3 = *(const float2*)&Wc1[(size_t)(k + 3) * 128 + jj];
#pragma unroll
            for (int i = 0; i < 8; i++) {
                const float4 a = *(const float4*)&sT2[eb + i][k];
                acc0[i] += a.x * w0.x + a.y * w1.x + a.z * w2.x + a.w * w3.x;
                acc1[i] += a.x * w0.y + a.y * w1.y + a.z * w2.y + a.w * w3.y;
            }
        }
        const float2 bc = *(const float2*)&bc1[jj];
        const float2 wc = *(const float2*)&Wc2[jj];
        float part[8];
#pragma unroll
        for (int i = 0; i < 8; i++)
            part[i] = silu(acc0[i] + bc.x) * wc.x + silu(acc1[i] + bc.y) * wc.y;
#pragma unroll
        for (int off = 32; off >= 1; off >>= 1) {
#pragma unroll
            for (int i = 0; i < 8; i++) part[i] += __shfl_xor(part[i], off, 64);
        }
        const int lane = t & 63;
        if (lane < 8) scoef[eb + lane] = part[lane];
    }
    __syncthreads();

    // Segment-reduce over the (dst-grouped) 32 edges, flush per distinct dst.
    if (t < 128) {
        const int j = t;
        float acc = sT2[0][j];
        int prev = sdst[0];
        for (int e2 = 1; e2 < 32; e2++) {
            const int de = sdst[e2];
            if (de != prev) {
                atomicAdd(&h_neigh[(size_t)prev * 128 + j], acc);
                acc = 0.0f;
                prev = de;
            }
            acc += sT2[e2][j];
        }
        atomicAdd(&h_neigh[(size_t)prev * 128 + j], acc);
    } else if (t < 131) {
        const int c = t - 128;
        float acc = scoef[0] * sxd[0][c];
        int prev = sdst[0];
        for (int e2 = 1; e2 < 32; e2++) {
            const int de = sdst[e2];
            if (de != prev) {
                atomicAdd(&xs[(size_t)prev * 4 + c], acc);
                acc = 0.0f;
                prev = de;
            }
            acc += scoef[e2] * sxd[e2][c];
        }
        atomicAdd(&xs[(size_t)prev * 4 + c], acc);
    }
}

// ---------------------------------------------------------------------------
// k_node: h = silu(nf@Wn1a + hn@Wn1b + bn1) @ Wn2 + bn2 ; x = coord + xs/cnt
// cnt comes from CSR degree (row_start diff) -- no atomics.
// ---------------------------------------------------------------------------
__global__ __launch_bounds__(256) void k_node(
    const float* __restrict__ nf, const float* __restrict__ coord,
    const float* __restrict__ hn, const float* __restrict__ xs,
    const int* __restrict__ row_start,
    const float* __restrict__ Wn1, const float* __restrict__ bn1,
    const float* __restrict__ Wn2, const float* __restrict__ bn2,
    float* __restrict__ out_h, float* __restrict__ out_x) {
    __shared__ float sA[32][128];
    __shared__ float sB[32][128];
    const int t = threadIdx.x;
    const int node0 = blockIdx.x * 32;
    {
        const int m = t >> 3, c = (t & 7) * 16;
        const float4* sp = (const float4*)&nf[(size_t)(node0 + m) * 128 + c];
        float4* dp = (float4*)&sA[m][c];
        dp[0] = sp[0]; dp[1] = sp[1]; dp[2] = sp[2]; dp[3] = sp[3];
        const float4* sp2 = (const float4*)&hn[(size_t)(node0 + m) * 128 + c];
        float4* dp2 = (float4*)&sB[m][c];
        dp2[0] = sp2[0]; dp2[1] = sp2[1]; dp2[2] = sp2[2]; dp2[3] = sp2[3];
    }
    if (t < 96) {
        const int m = t / 3, c = t - m * 3;
        const int i = node0 + m;
        const float cnt = (float)(row_start[i + 1] - row_start[i]);
        out_x[(size_t)i * 3 + c] =
            coord[(size_t)i * 3 + c] + xs[(size_t)i * 4 + c] / fmaxf(cnt, 1.0f);
    }
    __syncthreads();

    const int jj = (t & 63) * 2;
    const int mb = (t >> 6) * 8;

    float acc0[8], acc1[8];
#pragma unroll
    for (int i = 0; i < 8; i++) { acc0[i] = 0.0f; acc1[i] = 0.0f; }
    for (int k = 0; k < 128; k += 4) {
        const float2 w0 = *(const float2*)&Wn1[(size_t)(k + 0) * 128 + jj];
        const float2 w1 = *(const float2*)&Wn1[(size_t)(k + 1) * 128 + jj];
        const float2 w2 = *(const float2*)&Wn1[(size_t)(k + 2) * 128 + jj];
        const float2 w3 = *(const float2*)&Wn1[(size_t)(k + 3) * 128 + jj];
#pragma unroll
        for (int i = 0; i < 8; i++) {
            const float4 a = *(const float4*)&sA[mb + i][k];
            acc0[i] += a.x * w0.x + a.y * w1.x + a.z * w2.x + a.w * w3.x;
            acc1[i] += a.x * w0.y + a.y * w1.y + a.z * w2.y + a.w * w3.y;
        }
    }
    for (int k = 0; k < 128; k += 4) {
        const float2 w0 = *(const float2*)&Wn1[(size_t)(128 + k + 0) * 128 + jj];
        const float2 w1 = *(const float2*)&Wn1[(size_t)(128 + k + 1) * 128 + jj];
        const float2 w2 = *(const float2*)&Wn1[(size_t)(128 + k + 2) * 128 + jj];
        const float2 w3 = *(const float2*)&Wn1[(size_t)(128 + k + 3) * 128 + jj];
#pragma unroll
        for (int i = 0; i < 8; i++) {
            const float4 a = *(const float4*)&sB[mb + i][k];
            acc0[i] += a.x * w0.x + a.y * w1.x + a.z * w2.x + a.w * w3.x;
            acc1[i] += a.x * w0.y + a.y * w1.y + a.z * w2.y + a.w * w3.y;
        }
    }
    const float2 b1 = *(const float2*)&bn1[jj];
    __syncthreads();
#pragma unroll
    for (int i = 0; i < 8; i++) {
        float2 v;
        v.x = silu(acc0[i] + b1.x);
        v.y = silu(acc1[i] + b1.y);
        *(float2*)&sA[mb + i][jj] = v;
    }
    __syncthreads();

#pragma unroll
    for (int i = 0; i < 8; i++) { acc0[i] = 0.0f; acc1[i] = 0.0f; }
    for (int k = 0; k < 128; k += 4) {
        const float2 w0 = *(const float2*)&Wn2[(size_t)(k + 0) * 128 + jj];
        const float2 w1 = *(const float2*)&Wn2[(size_t)(k + 1) * 128 + jj];
        const float2 w2 = *(const float2*)&Wn2[(size_t)(k + 2) * 128 + jj];
        const float2 w3 = *(const float2*)&Wn2[(size_t)(k + 3) * 128 + jj];
#pragma unroll
        for (int i = 0; i < 8; i++) {
            const float4 a = *(const float4*)&sA[mb + i][k];
            acc0[i] += a.x * w0.x + a.y * w1.x + a.z * w2.x + a.w * w3.x;
            acc1[i] += a.x * w0.y + a.y * w1.y + a.z * w2.y + a.w * w3.y;
        }
    }
    const float2 b2 = *(const float2*)&bn2[jj];
#pragma unroll
    for (int i = 0; i < 8; i++) {
        float2 v;
        v.x = acc0[i] + b2.x;
        v.y = acc1[i] + b2.y;
        *(float2*)&out_h[(size_t)(node0 + mb + i) * 128 + jj] = v;
    }
}

// ---------------------------------------------------------------------------
extern "C" void kernel_launch(void* const* d_in, const int* in_sizes, int n_in,
                              void* d_out, int out_size, void* d_ws, size_t ws_size,
                              hipStream_t stream) {
    const float* nf    = (const float*)d_in[0];
    const float* coord = (const float*)d_in[1];
    const int*   src   = (const int*)d_in[2];
    const int*   dst   = (const int*)d_in[3];
    const float* We1   = (const float*)d_in[4];
    const float* be1   = (const float*)d_in[5];
    const float* We2   = (const float*)d_in[6];
    const float* be2   = (const float*)d_in[7];
    const float* Wn1   = (const float*)d_in[8];
    const float* bn1   = (const float*)d_in[9];
    const float* Wn2   = (const float*)d_in[10];
    const float* bn2   = (const float*)d_in[11];
    const float* Wc1   = (const float*)d_in[12];
    const float* bc1   = (const float*)d_in[13];
    const float* Wc2   = (const float*)d_in[14];

    float* P1 = (float*)d_ws;                          // N*128
    float* P2 = P1 + (size_t)N_NODES * 128;            // N*128
    float* hn = P2 + (size_t)N_NODES * 128;            // N*128
    float* xs = hn + (size_t)N_NODES * 128;            // N*4 (x sums, pad)
    int* deg       = (int*)(xs + (size_t)N_NODES * 4); // N
    int* row_start = deg + N_NODES;                    // N+1
    int* cursor    = row_start + N_NODES + 1;          // N
    int* elist     = cursor + N_NODES;                 // E

    float* out_h = (float*)d_out;                      // N*128
    float* out_x = out_h + (size_t)N_NODES * 128;      // N*3

    hipMemsetAsync(hn, 0, (size_t)N_NODES * 128 * sizeof(float), stream);
    hipMemsetAsync(xs, 0, (size_t)N_NODES * 4 * sizeof(float), stream);
    hipMemsetAsync(deg, 0, (size_t)N_NODES * sizeof(int), stream);
    hipMemsetAsync(cursor, 0, (size_t)N_NODES * sizeof(int), stream);

    k_count<<<(N_EDGES + 255) / 256, 256, 0, stream>>>(dst, deg);
    k_scan<<<1, 1024, 0, stream>>>(deg, row_start);
    k_fill<<<(N_EDGES + 255) / 256, 256, 0, stream>>>(dst, row_start, cursor, elist);
    k_pre<<<N_NODES / 32, 256, 0, stream>>>(nf, We1, P1, P2);
    k_edge2<<<N_EDGES / 32, 256, 0, stream>>>(P1, P2, coord, src, dst, elist,
                                              We1, be1, We2, be2, Wc1, bc1, Wc2,
                                              hn, xs);
    k_node<<<N_NODES / 32, 256, 0, stream>>>(nf, coord, hn, xs, row_start,
                                             Wn1, bn1, Wn2, bn2, out_h, out_x);
}

// Round 3
// 744.961 us; speedup vs baseline: 6.7055x; 1.6583x over previous
//
#include <hip/hip_runtime.h>
#include <math.h>
#include <stdint.h>

#define N_NODES 40000
#define N_EDGES 640000
#define D 128

typedef short short8 __attribute__((ext_vector_type(8)));
typedef float f32x4 __attribute__((ext_vector_type(4)));

__device__ __forceinline__ float silu(float x) { return x / (1.0f + __expf(-x)); }

__device__ __forceinline__ unsigned short f2bf(float f) {
    unsigned u = __float_as_uint(f);
    u += 0x7FFF + ((u >> 16) & 1);            // round-to-nearest-even
    return (unsigned short)(u >> 16);
}
__device__ __forceinline__ float bf2f(unsigned short h) {
    return __uint_as_float(((unsigned)h) << 16);
}

// ---------------------------------------------------------------------------
// CSR build: deg histogram -> exclusive scan -> fill permuted edge list.
// ---------------------------------------------------------------------------
__global__ __launch_bounds__(256) void k_count(const int* __restrict__ dst,
                                               int* __restrict__ deg) {
    const int e = blockIdx.x * 256 + threadIdx.x;
    if (e < N_EDGES) atomicAdd(&deg[dst[e]], 1);
}

__global__ __launch_bounds__(1024) void k_scan(const int* __restrict__ deg,
                                               int* __restrict__ row_start) {
    __shared__ int tmp[1024];
    __shared__ int base;
    const int t = threadIdx.x;
    if (t == 0) { base = 0; row_start[0] = 0; }
    __syncthreads();
    for (int off = 0; off < N_NODES; off += 1024) {
        int v = (off + t < N_NODES) ? deg[off + t] : 0;
        tmp[t] = v;
        __syncthreads();
        for (int s = 1; s < 1024; s <<= 1) {
            int u = (t >= s) ? tmp[t - s] : 0;
            __syncthreads();
            tmp[t] += u;
            __syncthreads();
        }
        const int b = base;
        if (off + t < N_NODES) row_start[off + t + 1] = b + tmp[t];
        __syncthreads();
        if (t == 0) base += tmp[1023];
        __syncthreads();
    }
}

__global__ __launch_bounds__(256) void k_fill(const int* __restrict__ dst,
                                              const int* __restrict__ row_start,
                                              int* __restrict__ cursor,
                                              int* __restrict__ elist) {
    const int e = blockIdx.x * 256 + threadIdx.x;
    if (e < N_EDGES) {
        const int d = dst[e];
        const int p = atomicAdd(&cursor[d], 1);
        elist[row_start[d] + p] = e;
    }
}

// ---------------------------------------------------------------------------
// k_pack: bf16-transposed weight packs. Wt[n][k] = bf16(W[k][n]).
// ---------------------------------------------------------------------------
__global__ __launch_bounds__(128) void k_pack(const float* __restrict__ We2,
                                              const float* __restrict__ Wc1,
                                              unsigned short* __restrict__ Wt_e2,
                                              unsigned short* __restrict__ Wt_c1) {
    const int n = blockIdx.x;
    const int k = threadIdx.x;
    Wt_e2[n * 128 + k] = f2bf(We2[k * 128 + n]);
    Wt_c1[n * 128 + k] = f2bf(Wc1[k * 128 + n]);
}

// ---------------------------------------------------------------------------
// k_pre: P1 = nf @ We1[0:128,:], P2 = nf @ We1[128:256,:]  (fp32)
// ---------------------------------------------------------------------------
__global__ __launch_bounds__(256) void k_pre(const float* __restrict__ nf,
                                             const float* __restrict__ We1,
                                             float* __restrict__ P1,
                                             float* __restrict__ P2) {
    __shared__ float sA[32][128];
    const int t = threadIdx.x;
    const int node0 = blockIdx.x * 32;
    {
        const int m = t >> 3, c = (t & 7) * 16;
        const float4* sp = (const float4*)&nf[(size_t)(node0 + m) * 128 + c];
        float4* dp = (float4*)&sA[m][c];
        dp[0] = sp[0]; dp[1] = sp[1]; dp[2] = sp[2]; dp[3] = sp[3];
    }
    __syncthreads();

    const int jj = t & 127;
    const int half = t >> 7;
    const float* W = We1 + (size_t)half * 128 * 128 + jj;

    float acc[32];
#pragma unroll
    for (int m = 0; m < 32; m++) acc[m] = 0.0f;

    for (int k = 0; k < 128; k += 4) {
        const float w0 = W[(size_t)(k + 0) * 128];
        const float w1 = W[(size_t)(k + 1) * 128];
        const float w2 = W[(size_t)(k + 2) * 128];
        const float w3 = W[(size_t)(k + 3) * 128];
#pragma unroll
        for (int m = 0; m < 32; m++) {
            const float4 a = *(const float4*)&sA[m][k];
            acc[m] += a.x * w0 + a.y * w1 + a.z * w2 + a.w * w3;
        }
    }
    float* P = half ? P2 : P1;
#pragma unroll
    for (int m = 0; m < 32; m++) P[(size_t)(node0 + m) * 128 + jj] = acc[m];
}

// ---------------------------------------------------------------------------
// k_edge3: 32 CSR-permuted edges per block, MFMA bf16 GEMMs.
//   wave w: edge-half h=w&1 (rows m0=h*16), col-half H=w>>1 (4 tiles of 16).
//   A-frag: A[m=lane&15][k=quad*8+j] from LDS (row stride 136 -> 2-way, free).
//   B-frag: Wt[n=lane&15][k=quad*8+j] from global (L2-resident pack).
//   C/D:    col=lane&15, row=quad*4+reg  (m89-verified layout).
// ---------------------------------------------------------------------------
__global__ __launch_bounds__(256) void k_edge3(
    const float* __restrict__ P1, const float* __restrict__ P2,
    const float* __restrict__ coord,
    const int* __restrict__ src, const int* __restrict__ dst,
    const int* __restrict__ elist,
    const float* __restrict__ We1, const float* __restrict__ be1,
    const unsigned short* __restrict__ Wt_e2, const float* __restrict__ be2,
    const unsigned short* __restrict__ Wt_c1, const float* __restrict__ bc1,
    const float* __restrict__ Wc2,
    float* __restrict__ h_neigh, float* __restrict__ xs) {
    __shared__ __align__(16) unsigned short sT1[32][136];
    __shared__ __align__(16) unsigned short sT2[32][136];
    __shared__ float scoefp[4][16];
    __shared__ float sdist[32];
    __shared__ float sxd[32][3];
    __shared__ int ssrc[32];
    __shared__ int sdst[32];

    const int t = threadIdx.x;
    const int e0 = blockIdx.x * 32;

    if (t < 32) {
        const int eid = elist[e0 + t];
        const int s = src[eid], d = dst[eid];
        ssrc[t] = s; sdst[t] = d;
        const float dx = coord[3 * s + 0] - coord[3 * d + 0];
        const float dy = coord[3 * s + 1] - coord[3 * d + 1];
        const float dz = coord[3 * s + 2] - coord[3 * d + 2];
        const float dist = sqrtf(dx * dx + dy * dy + dz * dz);
        sdist[t] = dist;
        const float inv = 1.0f / (dist + 1e-7f);
        sxd[t][0] = dx * inv; sxd[t][1] = dy * inv; sxd[t][2] = dz * inv;
    }
    __syncthreads();

    // t1 = silu(P1[s] + P2[d] + dist*We1[256] + be1), stored bf16
    {
        const int e = t >> 3;
        const int kc = (t & 7) * 16;
        const int s = ssrc[e], d = sdst[e];
        const float dist = sdist[e];
#pragma unroll
        for (int kk = 0; kk < 16; kk += 4) {
            const int k = kc + kk;
            const float4 a = *(const float4*)&P1[(size_t)s * 128 + k];
            const float4 b = *(const float4*)&P2[(size_t)d * 128 + k];
            const float4 w = *(const float4*)&We1[256 * 128 + k];
            const float4 bb = *(const float4*)&be1[k];
            sT1[e][k + 0] = f2bf(silu(a.x + b.x + dist * w.x + bb.x));
            sT1[e][k + 1] = f2bf(silu(a.y + b.y + dist * w.y + bb.y));
            sT1[e][k + 2] = f2bf(silu(a.z + b.z + dist * w.z + bb.z));
            sT1[e][k + 3] = f2bf(silu(a.w + b.w + dist * w.w + bb.w));
        }
    }
    __syncthreads();

    const int w = t >> 6;
    const int l = t & 63;
    const int h = w & 1;      // edge half
    const int H = w >> 1;     // col half
    const int m0 = h * 16;
    const int c = l & 15;
    const int quad = l >> 4;
    const int n0 = H * 64;

    // ---- GEMM1: t2 = silu(t1 @ We2 + be2) ----
    {
        f32x4 acc[4];
#pragma unroll
        for (int tile = 0; tile < 4; tile++) acc[tile] = (f32x4){0.f, 0.f, 0.f, 0.f};
#pragma unroll
        for (int k0 = 0; k0 < 128; k0 += 32) {
            const short8 a = *(const short8*)&sT1[m0 + c][k0 + quad * 8];
#pragma unroll
            for (int tile = 0; tile < 4; tile++) {
                const short8 b = *(const short8*)(Wt_e2 +
                    (((size_t)(n0 + tile * 16 + c)) << 7) + k0 + quad * 8);
                acc[tile] = __builtin_amdgcn_mfma_f32_16x16x32_bf16(a, b, acc[tile], 0, 0, 0);
            }
        }
#pragma unroll
        for (int tile = 0; tile < 4; tile++) {
            const int col = n0 + tile * 16 + c;
            const float bb = be2[col];
#pragma unroll
            for (int r = 0; r < 4; r++) {
                sT2[m0 + quad * 4 + r][col] = f2bf(silu(acc[tile][r] + bb));
            }
        }
    }
    __syncthreads();

    // ---- GEMM2: coef = silu(t2 @ Wc1 + bc1) . Wc2 ----
    {
        f32x4 acc[4];
#pragma unroll
        for (int tile = 0; tile < 4; tile++) acc[tile] = (f32x4){0.f, 0.f, 0.f, 0.f};
#pragma unroll
        for (int k0 = 0; k0 < 128; k0 += 32) {
            const short8 a = *(const short8*)&sT2[m0 + c][k0 + quad * 8];
#pragma unroll
            for (int tile = 0; tile < 4; tile++) {
                const short8 b = *(const short8*)(Wt_c1 +
                    (((size_t)(n0 + tile * 16 + c)) << 7) + k0 + quad * 8);
                acc[tile] = __builtin_amdgcn_mfma_f32_16x16x32_bf16(a, b, acc[tile], 0, 0, 0);
            }
        }
        float part[4] = {0.f, 0.f, 0.f, 0.f};
#pragma unroll
        for (int tile = 0; tile < 4; tile++) {
            const int col = n0 + tile * 16 + c;
            const float bc = bc1[col];
            const float wc = Wc2[col];
#pragma unroll
            for (int r = 0; r < 4; r++) part[r] += silu(acc[tile][r] + bc) * wc;
        }
#pragma unroll
        for (int off = 1; off < 16; off <<= 1) {
#pragma unroll
            for (int r = 0; r < 4; r++) part[r] += __shfl_xor(part[r], off, 64);
        }
        if (c == 0) {
#pragma unroll
            for (int r = 0; r < 4; r++) scoefp[w][quad * 4 + r] = part[r];
        }
    }
    __syncthreads();

    // ---- segment-reduced scatter (edges dst-grouped) ----
    if (t < 128) {
        const int j = t;
        float acc = bf2f(sT2[0][j]);
        int prev = sdst[0];
        for (int e2 = 1; e2 < 32; e2++) {
            const int de = sdst[e2];
            if (de != prev) {
                atomicAdd(&h_neigh[(size_t)prev * 128 + j], acc);
                acc = 0.0f;
                prev = de;
            }
            acc += bf2f(sT2[e2][j]);
        }
        atomicAdd(&h_neigh[(size_t)prev * 128 + j], acc);
    } else if (t < 131) {
        const int cc = t - 128;
        float coef0 = scoefp[0][0] + scoefp[2][0];
        float acc = coef0 * sxd[0][cc];
        int prev = sdst[0];
        for (int e2 = 1; e2 < 32; e2++) {
            const int de = sdst[e2];
            if (de != prev) {
                atomicAdd(&xs[(size_t)prev * 4 + cc], acc);
                acc = 0.0f;
                prev = de;
            }
            const float coef = scoefp[e2 >> 4][e2 & 15] + scoefp[(e2 >> 4) + 2][e2 & 15];
            acc += coef * sxd[e2][cc];
        }
        atomicAdd(&xs[(size_t)prev * 4 + cc], acc);
    }
}

// ---------------------------------------------------------------------------
// k_node: h = silu(nf@Wn1a + hn@Wn1b + bn1) @ Wn2 + bn2 ; x = coord + xs/cnt
// ---------------------------------------------------------------------------
__global__ __launch_bounds__(256) void k_node(
    const float* __restrict__ nf, const float* __restrict__ coord,
    const float* __restrict__ hn, const float* __restrict__ xs,
    const int* __restrict__ row_start,
    const float* __restrict__ Wn1, const float* __restrict__ bn1,
    const float* __restrict__ Wn2, const float* __restrict__ bn2,
    float* __restrict__ out_h, float* __restrict__ out_x) {
    __shared__ float sA[32][128];
    __shared__ float sB[32][128];
    const int t = threadIdx.x;
    const int node0 = blockIdx.x * 32;
    {
        const int m = t >> 3, c = (t & 7) * 16;
        const float4* sp = (const float4*)&nf[(size_t)(node0 + m) * 128 + c];
        float4* dp = (float4*)&sA[m][c];
        dp[0] = sp[0]; dp[1] = sp[1]; dp[2] = sp[2]; dp[3] = sp[3];
        const float4* sp2 = (const float4*)&hn[(size_t)(node0 + m) * 128 + c];
        float4* dp2 = (float4*)&sB[m][c];
        dp2[0] = sp2[0]; dp2[1] = sp2[1]; dp2[2] = sp2[2]; dp2[3] = sp2[3];
    }
    if (t < 96) {
        const int m = t / 3, c = t - m * 3;
        const int i = node0 + m;
        const float cnt = (float)(row_start[i + 1] - row_start[i]);
        out_x[(size_t)i * 3 + c] =
            coord[(size_t)i * 3 + c] + xs[(size_t)i * 4 + c] / fmaxf(cnt, 1.0f);
    }
    __syncthreads();

    const int jj = (t & 63) * 2;
    const int mb = (t >> 6) * 8;

    float acc0[8], acc1[8];
#pragma unroll
    for (int i = 0; i < 8; i++) { acc0[i] = 0.0f; acc1[i] = 0.0f; }
    for (int k = 0; k < 128; k += 4) {
        const float2 w0 = *(const float2*)&Wn1[(size_t)(k + 0) * 128 + jj];
        const float2 w1 = *(const float2*)&Wn1[(size_t)(k + 1) * 128 + jj];
        const float2 w2 = *(const float2*)&Wn1[(size_t)(k + 2) * 128 + jj];
        const float2 w3 = *(const float2*)&Wn1[(size_t)(k + 3) * 128 + jj];
#pragma unroll
        for (int i = 0; i < 8; i++) {
            const float4 a = *(const float4*)&sA[mb + i][k];
            acc0[i] += a.x * w0.x + a.y * w1.x + a.z * w2.x + a.w * w3.x;
            acc1[i] += a.x * w0.y + a.y * w1.y + a.z * w2.y + a.w * w3.y;
        }
    }
    for (int k = 0; k < 128; k += 4) {
        const float2 w0 = *(const float2*)&Wn1[(size_t)(128 + k + 0) * 128 + jj];
        const float2 w1 = *(const float2*)&Wn1[(size_t)(128 + k + 1) * 128 + jj];
        const float2 w2 = *(const float2*)&Wn1[(size_t)(128 + k + 2) * 128 + jj];
        const float2 w3 = *(const float2*)&Wn1[(size_t)(128 + k + 3) * 128 + jj];
#pragma unroll
        for (int i = 0; i < 8; i++) {
            const float4 a = *(const float4*)&sB[mb + i][k];
            acc0[i] += a.x * w0.x + a.y * w1.x + a.z * w2.x + a.w * w3.x;
            acc1[i] += a.x * w0.y + a.y * w1.y + a.z * w2.y + a.w * w3.y;
        }
    }
    const float2 b1 = *(const float2*)&bn1[jj];
    __syncthreads();
#pragma unroll
    for (int i = 0; i < 8; i++) {
        float2 v;
        v.x = silu(acc0[i] + b1.x);
        v.y = silu(acc1[i] + b1.y);
        *(float2*)&sA[mb + i][jj] = v;
    }
    __syncthreads();

#pragma unroll
    for (int i = 0; i < 8; i++) { acc0[i] = 0.0f; acc1[i] = 0.0f; }
    for (int k = 0; k < 128; k += 4) {
        const float2 w0 = *(const float2*)&Wn2[(size_t)(k + 0) * 128 + jj];
        const float2 w1 = *(const float2*)&Wn2[(size_t)(k + 1) * 128 + jj];
        const float2 w2 = *(const float2*)&Wn2[(size_t)(k + 2) * 128 + jj];
        const float2 w3 = *(const float2*)&Wn2[(size_t)(k + 3) * 128 + jj];
#pragma unroll
        for (int i = 0; i < 8; i++) {
            const float4 a = *(const float4*)&sA[mb + i][k];
            acc0[i] += a.x * w0.x + a.y * w1.x + a.z * w2.x + a.w * w3.x;
            acc1[i] += a.x * w0.y + a.y * w1.y + a.z * w2.y + a.w * w3.y;
        }
    }
    const float2 b2 = *(const float2*)&bn2[jj];
#pragma unroll
    for (int i = 0; i < 8; i++) {
        float2 v;
        v.x = acc0[i] + b2.x;
        v.y = acc1[i] + b2.y;
        *(float2*)&out_h[(size_t)(node0 + mb + i) * 128 + jj] = v;
    }
}

// ---------------------------------------------------------------------------
extern "C" void kernel_launch(void* const* d_in, const int* in_sizes, int n_in,
                              void* d_out, int out_size, void* d_ws, size_t ws_size,
                              hipStream_t stream) {
    const float* nf    = (const float*)d_in[0];
    const float* coord = (const float*)d_in[1];
    const int*   src   = (const int*)d_in[2];
    const int*   dst   = (const int*)d_in[3];
    const float* We1   = (const float*)d_in[4];
    const float* be1   = (const float*)d_in[5];
    const float* We2   = (const float*)d_in[6];
    const float* be2   = (const float*)d_in[7];
    const float* Wn1   = (const float*)d_in[8];
    const float* bn1   = (const float*)d_in[9];
    const float* Wn2   = (const float*)d_in[10];
    const float* bn2   = (const float*)d_in[11];
    const float* Wc1   = (const float*)d_in[12];
    const float* bc1   = (const float*)d_in[13];
    const float* Wc2   = (const float*)d_in[14];

    float* P1 = (float*)d_ws;                          // N*128
    float* P2 = P1 + (size_t)N_NODES * 128;            // N*128
    float* hn = P2 + (size_t)N_NODES * 128;            // N*128
    float* xs = hn + (size_t)N_NODES * 128;            // N*4
    int* deg       = (int*)(xs + (size_t)N_NODES * 4); // N
    int* row_start = deg + N_NODES;                    // N+1
    int* cursor    = row_start + N_NODES + 1;          // N
    int* elist     = cursor + N_NODES;                 // E
    unsigned short* Wt_e2 = (unsigned short*)
        (((uintptr_t)(elist + N_EDGES) + 255) & ~(uintptr_t)255);  // 128*128 bf16
    unsigned short* Wt_c1 = Wt_e2 + 128 * 128;                     // 128*128 bf16

    float* out_h = (float*)d_out;                      // N*128
    float* out_x = out_h + (size_t)N_NODES * 128;      // N*3

    hipMemsetAsync(hn, 0, (size_t)N_NODES * 128 * sizeof(float), stream);
    hipMemsetAsync(xs, 0, (size_t)N_NODES * 4 * sizeof(float), stream);
    hipMemsetAsync(deg, 0, (size_t)N_NODES * sizeof(int), stream);
    hipMemsetAsync(cursor, 0, (size_t)N_NODES * sizeof(int), stream);

    k_pack<<<128, 128, 0, stream>>>(We2, Wc1, Wt_e2, Wt_c1);
    k_count<<<(N_EDGES + 255) / 256, 256, 0, stream>>>(dst, deg);
    k_scan<<<1, 1024, 0, stream>>>(deg, row_start);
    k_fill<<<(N_EDGES + 255) / 256, 256, 0, stream>>>(dst, row_start, cursor, elist);
    k_pre<<<N_NODES / 32, 256, 0, stream>>>(nf, We1, P1, P2);
    k_edge3<<<N_EDGES / 32, 256, 0, stream>>>(P1, P2, coord, src, dst, elist,
                                              We1, be1, Wt_e2, be2, Wt_c1, bc1,
                                              Wc2, hn, xs);
    k_node<<<N_NODES / 32, 256, 0, stream>>>(nf, coord, hn, xs, row_start,
                                             Wn1, bn1, Wn2, bn2, out_h, out_x);
}

// Round 6
// 611.135 us; speedup vs baseline: 8.1739x; 1.2190x over previous
//
#include <hip/hip_runtime.h>
#include <math.h>
#include <stdint.h>

#define N_NODES 40000
#define N_EDGES 640000

typedef short short8 __attribute__((ext_vector_type(8)));
typedef float f32x4 __attribute__((ext_vector_type(4)));

__device__ __forceinline__ float silu(float x) { return x / (1.0f + __expf(-x)); }

__device__ __forceinline__ unsigned short f2bf(float f) {
    unsigned u = __float_as_uint(f);
    u += 0x7FFF + ((u >> 16) & 1);            // round-to-nearest-even
    return (unsigned short)(u >> 16);
}
__device__ __forceinline__ float bf2f(unsigned short h) {
    return __uint_as_float(((unsigned)h) << 16);
}

// ---------------------------------------------------------------------------
// CSR build: deg histogram -> exclusive scan -> fill permuted edge list.
// ---------------------------------------------------------------------------
__global__ __launch_bounds__(256) void k_count(const int* __restrict__ dst,
                                               int* __restrict__ deg) {
    const int e = blockIdx.x * 256 + threadIdx.x;
    if (e < N_EDGES) atomicAdd(&deg[dst[e]], 1);
}

__global__ __launch_bounds__(1024) void k_scan(const int* __restrict__ deg,
                                               int* __restrict__ row_start) {
    __shared__ int tmp[1024];
    __shared__ int base;
    const int t = threadIdx.x;
    if (t == 0) { base = 0; row_start[0] = 0; }
    __syncthreads();
    for (int off = 0; off < N_NODES; off += 1024) {
        int v = (off + t < N_NODES) ? deg[off + t] : 0;
        tmp[t] = v;
        __syncthreads();
        for (int s = 1; s < 1024; s <<= 1) {
            int u = (t >= s) ? tmp[t - s] : 0;
            __syncthreads();
            tmp[t] += u;
            __syncthreads();
        }
        const int b = base;
        if (off + t < N_NODES) row_start[off + t + 1] = b + tmp[t];
        __syncthreads();
        if (t == 0) base += tmp[1023];
        __syncthreads();
    }
}

__global__ __launch_bounds__(256) void k_fill(const int* __restrict__ dst,
                                              const int* __restrict__ row_start,
                                              int* __restrict__ cursor,
                                              int* __restrict__ elist) {
    const int e = blockIdx.x * 256 + threadIdx.x;
    if (e < N_EDGES) {
        const int d = dst[e];
        const int p = atomicAdd(&cursor[d], 1);
        elist[row_start[d] + p] = e;
    }
}

// ---------------------------------------------------------------------------
// k_pack2: all bf16-transposed weight packs. Wt[n][k] = bf16(W[k][n]).
//   Wt_e1[256][128]  (We1 rows 0..255; col j of P1 -> n=j, of P2 -> n=128+j)
//   Wt_e2/Wt_c1/Wt_n2[128][128], Wt_n1[128][256]
// ---------------------------------------------------------------------------
__global__ __launch_bounds__(128) void k_pack2(
    const float* __restrict__ We1, const float* __restrict__ We2,
    const float* __restrict__ Wc1, const float* __restrict__ Wn1,
    const float* __restrict__ Wn2,
    unsigned short* __restrict__ Wt_e1, unsigned short* __restrict__ Wt_e2,
    unsigned short* __restrict__ Wt_c1, unsigned short* __restrict__ Wt_n1,
    unsigned short* __restrict__ Wt_n2) {
    const int b = blockIdx.x;   // 0..255
    const int t = threadIdx.x;  // 0..127
    Wt_e1[b * 128 + t] = f2bf(We1[(size_t)((b >> 7) * 128 + t) * 128 + (b & 127)]);
    if (b < 128) {
        Wt_e2[b * 128 + t] = f2bf(We2[(size_t)t * 128 + b]);
        Wt_c1[b * 128 + t] = f2bf(Wc1[(size_t)t * 128 + b]);
        Wt_n2[b * 128 + t] = f2bf(Wn2[(size_t)t * 128 + b]);
        Wt_n1[b * 256 + t] = f2bf(Wn1[(size_t)t * 128 + b]);
        Wt_n1[b * 256 + 128 + t] = f2bf(Wn1[(size_t)(128 + t) * 128 + b]);
    }
}

// ---------------------------------------------------------------------------
// k_pre (MFMA): Pc[node][0:128]=nf@We1a, Pc[node][128:256]=nf@We1b, bf16 out.
// 32 nodes/block, 4 waves; wave w covers 64 of 256 output cols.
// ---------------------------------------------------------------------------
__global__ __launch_bounds__(256) void k_pre(
    const float* __restrict__ nf, const unsigned short* __restrict__ Wt_e1,
    unsigned short* __restrict__ Pc) {
    __shared__ __align__(16) unsigned short sNF[32][136];
    const int t = threadIdx.x;
    const int node0 = blockIdx.x * 32;
    {
        const int m = t >> 3, kc = (t & 7) * 16;
        const float* sp = &nf[(size_t)(node0 + m) * 128 + kc];
#pragma unroll
        for (int kk = 0; kk < 16; kk += 4) {
            const float4 v = *(const float4*)(sp + kk);
            sNF[m][kc + kk + 0] = f2bf(v.x);
            sNF[m][kc + kk + 1] = f2bf(v.y);
            sNF[m][kc + kk + 2] = f2bf(v.z);
            sNF[m][kc + kk + 3] = f2bf(v.w);
        }
    }
    __syncthreads();

    const int w = t >> 6, l = t & 63, c = l & 15, quad = l >> 4;
    const int n0 = w * 64;

    f32x4 acc[2][4];
#pragma unroll
    for (int mt = 0; mt < 2; mt++)
#pragma unroll
        for (int tile = 0; tile < 4; tile++) acc[mt][tile] = (f32x4){0.f, 0.f, 0.f, 0.f};

#pragma unroll
    for (int k0 = 0; k0 < 128; k0 += 32) {
        const short8 a0 = *(const short8*)&sNF[c][k0 + quad * 8];
        const short8 a1 = *(const short8*)&sNF[16 + c][k0 + quad * 8];
#pragma unroll
        for (int tile = 0; tile < 4; tile++) {
            const short8 b = *(const short8*)(Wt_e1 +
                ((size_t)(n0 + tile * 16 + c) << 7) + k0 + quad * 8);
            acc[0][tile] = __builtin_amdgcn_mfma_f32_16x16x32_bf16(a0, b, acc[0][tile], 0, 0, 0);
            acc[1][tile] = __builtin_amdgcn_mfma_f32_16x16x32_bf16(a1, b, acc[1][tile], 0, 0, 0);
        }
    }
#pragma unroll
    for (int mt = 0; mt < 2; mt++)
#pragma unroll
        for (int tile = 0; tile < 4; tile++) {
            const int col = n0 + tile * 16 + c;
#pragma unroll
            for (int r = 0; r < 4; r++) {
                const int row = mt * 16 + quad * 4 + r;
                Pc[(size_t)(node0 + row) * 256 + col] = f2bf(acc[mt][tile][r]);
            }
        }
}

// ---------------------------------------------------------------------------
// k_edge4: 64 CSR-permuted edges per 512-thread block (8 waves).
//   wave w: edge quarter h=w&3 (m0=h*16), col half H=w>>2 (n0=H*64).
//   Full-width segment-reduced scatter (4 quarters x 128 cols in parallel).
// ---------------------------------------------------------------------------
__global__ __launch_bounds__(512) void k_edge4(
    const unsigned short* __restrict__ Pc, const float* __restrict__ coord,
    const int* __restrict__ src, const int* __restrict__ dst,
    const int* __restrict__ elist,
    const float* __restrict__ We1, const float* __restrict__ be1,
    const unsigned short* __restrict__ Wt_e2, const float* __restrict__ be2,
    const unsigned short* __restrict__ Wt_c1, const float* __restrict__ bc1,
    const float* __restrict__ Wc2,
    float* __restrict__ h_neigh, float* __restrict__ xs) {
    __shared__ __align__(16) unsigned short sT1[64][136];
    __shared__ __align__(16) unsigned short sT2[64][136];
    __shared__ float scoefp[8][16];
    __shared__ float sw[128], sb[128];
    __shared__ float sdist[64];
    __shared__ float sxd[64][3];
    __shared__ int ssrc[64];
    __shared__ int sdst[64];

    const int t = threadIdx.x;
    const int e0 = blockIdx.x * 64;

    if (t < 64) {
        const int eid = elist[e0 + t];
        const int s = src[eid], d = dst[eid];
        ssrc[t] = s; sdst[t] = d;
        const float dx = coord[3 * s + 0] - coord[3 * d + 0];
        const float dy = coord[3 * s + 1] - coord[3 * d + 1];
        const float dz = coord[3 * s + 2] - coord[3 * d + 2];
        const float dist = sqrtf(dx * dx + dy * dy + dz * dz);
        sdist[t] = dist;
        const float inv = 1.0f / (dist + 1e-7f);
        sxd[t][0] = dx * inv; sxd[t][1] = dy * inv; sxd[t][2] = dz * inv;
    } else if (t < 96) {
        ((float4*)sw)[t - 64] = ((const float4*)(We1 + 256 * 128))[t - 64];
    } else if (t < 128) {
        ((float4*)sb)[t - 96] = ((const float4*)be1)[t - 96];
    }
    __syncthreads();

    // t1 = silu(P1[s] + P2[d] + dist*We1[256] + be1), stored bf16
    {
        const int e = t >> 3;
        const int kc = (t & 7) * 16;
        const int s = ssrc[e], d = sdst[e];
        const float dist = sdist[e];
        const unsigned short* p1 = Pc + (size_t)s * 256 + kc;
        const unsigned short* p2 = Pc + (size_t)d * 256 + 128 + kc;
        const short8 a0 = *(const short8*)p1;
        const short8 a1 = *(const short8*)(p1 + 8);
        const short8 b0 = *(const short8*)p2;
        const short8 b1 = *(const short8*)(p2 + 8);
#pragma unroll
        for (int kk = 0; kk < 8; kk++) {
            const float v = bf2f((unsigned short)a0[kk]) + bf2f((unsigned short)b0[kk])
                          + dist * sw[kc + kk] + sb[kc + kk];
            sT1[e][kc + kk] = f2bf(silu(v));
        }
#pragma unroll
        for (int kk = 0; kk < 8; kk++) {
            const float v = bf2f((unsigned short)a1[kk]) + bf2f((unsigned short)b1[kk])
                          + dist * sw[kc + 8 + kk] + sb[kc + 8 + kk];
            sT1[e][kc + 8 + kk] = f2bf(silu(v));
        }
    }
    __syncthreads();

    const int w = t >> 6;
    const int l = t & 63;
    const int h = w & 3;      // edge quarter
    const int H = w >> 2;     // col half
    const int m0 = h * 16;
    const int n0 = H * 64;
    const int c = l & 15;
    const int quad = l >> 4;

    // ---- GEMM1: t2 = silu(t1 @ We2 + be2) ----
    {
        f32x4 acc[4];
#pragma unroll
        for (int tile = 0; tile < 4; tile++) acc[tile] = (f32x4){0.f, 0.f, 0.f, 0.f};
#pragma unroll
        for (int k0 = 0; k0 < 128; k0 += 32) {
            const short8 a = *(const short8*)&sT1[m0 + c][k0 + quad * 8];
#pragma unroll
            for (int tile = 0; tile < 4; tile++) {
                const short8 b = *(const short8*)(Wt_e2 +
                    ((size_t)(n0 + tile * 16 + c) << 7) + k0 + quad * 8);
                acc[tile] = __builtin_amdgcn_mfma_f32_16x16x32_bf16(a, b, acc[tile], 0, 0, 0);
            }
        }
#pragma unroll
        for (int tile = 0; tile < 4; tile++) {
            const int col = n0 + tile * 16 + c;
            const float bb = be2[col];
#pragma unroll
            for (int r = 0; r < 4; r++) {
                sT2[m0 + quad * 4 + r][col] = f2bf(silu(acc[tile][r] + bb));
            }
        }
    }
    __syncthreads();

    // ---- GEMM2: coef = silu(t2 @ Wc1 + bc1) . Wc2 ----
    {
        f32x4 acc[4];
#pragma unroll
        for (int tile = 0; tile < 4; tile++) acc[tile] = (f32x4){0.f, 0.f, 0.f, 0.f};
#pragma unroll
        for (int k0 = 0; k0 < 128; k0 += 32) {
            const short8 a = *(const short8*)&sT2[m0 + c][k0 + quad * 8];
#pragma unroll
            for (int tile = 0; tile < 4; tile++) {
                const short8 b = *(const short8*)(Wt_c1 +
                    ((size_t)(n0 + tile * 16 + c) << 7) + k0 + quad * 8);
                acc[tile] = __builtin_amdgcn_mfma_f32_16x16x32_bf16(a, b, acc[tile], 0, 0, 0);
            }
        }
        float part[4] = {0.f, 0.f, 0.f, 0.f};
#pragma unroll
        for (int tile = 0; tile < 4; tile++) {
            const int col = n0 + tile * 16 + c;
            const float bc = bc1[col];
            const float wc = Wc2[col];
#pragma unroll
            for (int r = 0; r < 4; r++) part[r] += silu(acc[tile][r] + bc) * wc;
        }
#pragma unroll
        for (int off = 1; off < 16; off <<= 1) {
#pragma unroll
            for (int r = 0; r < 4; r++) part[r] += __shfl_xor(part[r], off, 64);
        }
        if (c == 0) {
#pragma unroll
            for (int r = 0; r < 4; r++) scoefp[w][quad * 4 + r] = part[r];
        }
    }
    __syncthreads();

    // ---- segment-reduced scatter: all 512 threads; quarter q, column j ----
    {
        const int j = t & 127;
        const int q = t >> 7;
        const int eb = q * 16;
        float acc = bf2f(sT2[eb][j]);
        int prev = sdst[eb];
        for (int e2 = eb + 1; e2 < eb + 16; e2++) {
            const int de = sdst[e2];
            if (de != prev) {
                atomicAdd(&h_neigh[(size_t)prev * 128 + j], acc);
                acc = 0.0f;
                prev = de;
            }
            acc += bf2f(sT2[e2][j]);
        }
        atomicAdd(&h_neigh[(size_t)prev * 128 + j], acc);
    }
    if (t < 12) {
        const int q = t / 3, cc = t - q * 3;
        const int eb = q * 16;
        float coef = scoefp[eb >> 4][eb & 15] + scoefp[(eb >> 4) + 4][eb & 15];
        float acc = coef * sxd[eb][cc];
        int prev = sdst[eb];
        for (int e2 = eb + 1; e2 < eb + 16; e2++) {
            const int de = sdst[e2];
            if (de != prev) {
                atomicAdd(&xs[(size_t)prev * 4 + cc], acc);
                acc = 0.0f;
                prev = de;
            }
            coef = scoefp[e2 >> 4][e2 & 15] + scoefp[(e2 >> 4) + 4][e2 & 15];
            acc += coef * sxd[e2][cc];
        }
        atomicAdd(&xs[(size_t)prev * 4 + cc], acc);
    }
}

// ---------------------------------------------------------------------------
// k_node (MFMA): h = silu([nf|hn] @ Wn1 + bn1) @ Wn2 + bn2 ; x = coord+xs/cnt
// 32 nodes/block, 4 waves; wave w covers 32 of 128 output cols.
// ---------------------------------------------------------------------------
__global__ __launch_bounds__(256) void k_node(
    const float* __restrict__ nf, const float* __restrict__ coord,
    const float* __restrict__ hn, const float* __restrict__ xs,
    const int* __restrict__ row_start,
    const unsigned short* __restrict__ Wt_n1, const float* __restrict__ bn1,
    const unsigned short* __restrict__ Wt_n2, const float* __restrict__ bn2,
    float* __restrict__ out_h, float* __restrict__ out_x) {
    __shared__ __align__(16) unsigned short sAB[32][264];
    __shared__ __align__(16) unsigned short sH[32][136];
    const int t = threadIdx.x;
    const int node0 = blockIdx.x * 32;
    {
        const int m = t >> 3, kc = (t & 7) * 32;
        const float* base = (kc < 128) ? &nf[(size_t)(node0 + m) * 128 + kc]
                                       : &hn[(size_t)(node0 + m) * 128 + (kc - 128)];
#pragma unroll
        for (int kk = 0; kk < 32; kk += 4) {
            const float4 v = *(const float4*)(base + kk);
            sAB[m][kc + kk + 0] = f2bf(v.x);
            sAB[m][kc + kk + 1] = f2bf(v.y);
            sAB[m][kc + kk + 2] = f2bf(v.z);
            sAB[m][kc + kk + 3] = f2bf(v.w);
        }
    }
    if (t < 96) {
        const int m = t / 3, cc = t - m * 3;
        const int i = node0 + m;
        const float cnt = (float)(row_start[i + 1] - row_start[i]);
        out_x[(size_t)i * 3 + cc] =
            coord[(size_t)i * 3 + cc] + xs[(size_t)i * 4 + cc] / fmaxf(cnt, 1.0f);
    }
    __syncthreads();

    const int w = t >> 6, l = t & 63, c = l & 15, quad = l >> 4;
    const int n0 = w * 32;

    // GEMM1: M=32, K=256, N=128
    {
        f32x4 acc[2][2];
#pragma unroll
        for (int mt = 0; mt < 2; mt++)
#pragma unroll
            for (int tile = 0; tile < 2; tile++) acc[mt][tile] = (f32x4){0.f, 0.f, 0.f, 0.f};
#pragma unroll
        for (int k0 = 0; k0 < 256; k0 += 32) {
            const short8 a0 = *(const short8*)&sAB[c][k0 + quad * 8];
            const short8 a1 = *(const short8*)&sAB[16 + c][k0 + quad * 8];
#pragma unroll
            for (int tile = 0; tile < 2; tile++) {
                const short8 b = *(const short8*)(Wt_n1 +
                    ((size_t)(n0 + tile * 16 + c) << 8) + k0 + quad * 8);
                acc[0][tile] = __builtin_amdgcn_mfma_f32_16x16x32_bf16(a0, b, acc[0][tile], 0, 0, 0);
                acc[1][tile] = __builtin_amdgcn_mfma_f32_16x16x32_bf16(a1, b, acc[1][tile], 0, 0, 0);
            }
        }
#pragma unroll
        for (int mt = 0; mt < 2; mt++)
#pragma unroll
            for (int tile = 0; tile < 2; tile++) {
                const int col = n0 + tile * 16 + c;
                const float bb = bn1[col];
#pragma unroll
                for (int r = 0; r < 4; r++) {
                    sH[mt * 16 + quad * 4 + r][col] = f2bf(silu(acc[mt][tile][r] + bb));
                }
            }
    }
    __syncthreads();

    // GEMM2: M=32, K=128, N=128
    {
        f32x4 acc[2][2];
#pragma unroll
        for (int mt = 0; mt < 2; mt++)
#pragma unroll
            for (int tile = 0; tile < 2; tile++) acc[mt][tile] = (f32x4){0.f, 0.f, 0.f, 0.f};
#pragma unroll
        for (int k0 = 0; k0 < 128; k0 += 32) {
            const short8 a0 = *(const short8*)&sH[c][k0 + quad * 8];
            const short8 a1 = *(const short8*)&sH[16 + c][k0 + quad * 8];
#pragma unroll
            for (int tile = 0; tile < 2; tile++) {
                const short8 b = *(const short8*)(Wt_n2 +
                    ((size_t)(n0 + tile * 16 + c) << 7) + k0 + quad * 8);
                acc[0][tile] = __builtin_amdgcn_mfma_f32_16x16x32_bf16(a0, b, acc[0][tile], 0, 0, 0);
                acc[1][tile] = __builtin_amdgcn_mfma_f32_16x16x32_bf16(a1, b, acc[1][tile], 0, 0, 0);
            }
        }
#pragma unroll
        for (int mt = 0; mt < 2; mt++)
#pragma unroll
            for (int tile = 0; tile < 2; tile++) {
                const int col = n0 + tile * 16 + c;
                const float bb = bn2[col];
#pragma unroll
                for (int r = 0; r < 4; r++) {
                    const int row = mt * 16 + quad * 4 + r;
                    out_h[(size_t)(node0 + row) * 128 + col] = acc[mt][tile][r] + bb;
                }
            }
    }
}

// ---------------------------------------------------------------------------
extern "C" void kernel_launch(void* const* d_in, const int* in_sizes, int n_in,
                              void* d_out, int out_size, void* d_ws, size_t ws_size,
                              hipStream_t stream) {
    const float* nf    = (const float*)d_in[0];
    const float* coord = (const float*)d_in[1];
    const int*   src   = (const int*)d_in[2];
    const int*   dst   = (const int*)d_in[3];
    const float* We1   = (const float*)d_in[4];
    const float* be1   = (const float*)d_in[5];
    const float* We2   = (const float*)d_in[6];
    const float* be2   = (const float*)d_in[7];
    const float* Wn1   = (const float*)d_in[8];
    const float* bn1   = (const float*)d_in[9];
    const float* Wn2   = (const float*)d_in[10];
    const float* bn2   = (const float*)d_in[11];
    const float* Wc1   = (const float*)d_in[12];
    const float* bc1   = (const float*)d_in[13];
    const float* Wc2   = (const float*)d_in[14];

    unsigned short* Pc = (unsigned short*)d_ws;            // N*256 bf16
    float* hn = (float*)(Pc + (size_t)N_NODES * 256);      // N*128 f32
    float* xs = hn + (size_t)N_NODES * 128;                // N*4
    int* deg       = (int*)(xs + (size_t)N_NODES * 4);     // N
    int* row_start = deg + N_NODES;                        // N+1
    int* cursor    = row_start + N_NODES + 1;              // N
    int* elist     = cursor + N_NODES;                     // E
    unsigned short* Wt_e1 = (unsigned short*)
        (((uintptr_t)(elist + N_EDGES) + 255) & ~(uintptr_t)255);  // 256*128
    unsigned short* Wt_e2 = Wt_e1 + 256 * 128;                     // 128*128
    unsigned short* Wt_c1 = Wt_e2 + 128 * 128;                     // 128*128
    unsigned short* Wt_n1 = Wt_c1 + 128 * 128;                     // 128*256
    unsigned short* Wt_n2 = Wt_n1 + 128 * 256;                     // 128*128

    float* out_h = (float*)d_out;                          // N*128
    float* out_x = out_h + (size_t)N_NODES * 128;          // N*3

    hipMemsetAsync(hn, 0, (size_t)N_NODES * 128 * sizeof(float), stream);
    hipMemsetAsync(xs, 0, (size_t)N_NODES * 4 * sizeof(float), stream);
    hipMemsetAsync(deg, 0, (size_t)N_NODES * sizeof(int), stream);
    hipMemsetAsync(cursor, 0, (size_t)N_NODES * sizeof(int), stream);

    k_pack2<<<256, 128, 0, stream>>>(We1, We2, Wc1, Wn1, Wn2,
                                     Wt_e1, Wt_e2, Wt_c1, Wt_n1, Wt_n2);
    k_count<<<(N_EDGES + 255) / 256, 256, 0, stream>>>(dst, deg);
    k_scan<<<1, 1024, 0, stream>>>(deg, row_start);
    k_fill<<<(N_EDGES + 255) / 256, 256, 0, stream>>>(dst, row_start, cursor, elist);
    k_pre<<<N_NODES / 32, 256, 0, stream>>>(nf, Wt_e1, Pc);
    k_edge4<<<N_EDGES / 64, 512, 0, stream>>>(Pc, coord, src, dst, elist,
                                              We1, be1, Wt_e2, be2, Wt_c1, bc1,
                                              Wc2, hn, xs);
    k_node<<<N_NODES / 32, 256, 0, stream>>>(nf, coord, hn, xs, row_start,
                                             Wt_n1, bn1, Wt_n2, bn2, out_h, out_x);
}

// Round 7
// 561.757 us; speedup vs baseline: 8.8924x; 1.0879x over previous
//
#include <hip/hip_runtime.h>
#include <math.h>
#include <stdint.h>

#define N_NODES 40000
#define N_EDGES 640000

typedef short short8 __attribute__((ext_vector_type(8)));
typedef float f32x4 __attribute__((ext_vector_type(4)));

__device__ __forceinline__ float silu(float x) { return x / (1.0f + __expf(-x)); }

__device__ __forceinline__ unsigned short f2bf(float f) {
    unsigned u = __float_as_uint(f);
    u += 0x7FFF + ((u >> 16) & 1);            // round-to-nearest-even
    return (unsigned short)(u >> 16);
}
__device__ __forceinline__ float bf2f(unsigned short h) {
    return __uint_as_float(((unsigned)h) << 16);
}

// ---------------------------------------------------------------------------
// CSR build: deg histogram -> exclusive scan -> fill permuted edge list.
// ---------------------------------------------------------------------------
__global__ __launch_bounds__(256) void k_count(const int* __restrict__ dst,
                                               int* __restrict__ deg) {
    const int e = blockIdx.x * 256 + threadIdx.x;
    if (e < N_EDGES) atomicAdd(&deg[dst[e]], 1);
}

// Shuffle-based hierarchical scan: 3 barriers/chunk (was ~20).
__global__ __launch_bounds__(1024) void k_scan(const int* __restrict__ deg,
                                               int* __restrict__ row_start) {
    __shared__ int wsum[16];
    const int t = threadIdx.x;
    const int lane = t & 63, wid = t >> 6;
    int base = 0;
    if (t == 0) row_start[0] = 0;
    for (int off = 0; off < N_NODES; off += 1024) {
        int x = (off + t < N_NODES) ? deg[off + t] : 0;
#pragma unroll
        for (int s = 1; s < 64; s <<= 1) {
            const int u = __shfl_up(x, s, 64);
            if (lane >= s) x += u;
        }
        if (lane == 63) wsum[wid] = x;
        __syncthreads();
        if (wid == 0) {
            int ws = (lane < 16) ? wsum[lane] : 0;
#pragma unroll
            for (int s = 1; s < 16; s <<= 1) {
                const int u = __shfl_up(ws, s, 64);
                if (lane >= s) ws += u;
            }
            if (lane < 16) wsum[lane] = ws;
        }
        __syncthreads();
        const int wbase = (wid > 0) ? wsum[wid - 1] : 0;
        const int total = wsum[15];
        if (off + t < N_NODES) row_start[off + t + 1] = base + wbase + x;
        base += total;
        __syncthreads();   // wsum reads done before next chunk overwrites
    }
}

__global__ __launch_bounds__(256) void k_fill(const int* __restrict__ dst,
                                              const int* __restrict__ row_start,
                                              int* __restrict__ cursor,
                                              int* __restrict__ elist) {
    const int e = blockIdx.x * 256 + threadIdx.x;
    if (e < N_EDGES) {
        const int d = dst[e];
        const int p = atomicAdd(&cursor[d], 1);
        elist[row_start[d] + p] = e;
    }
}

// ---------------------------------------------------------------------------
// k_pack2: bf16-transposed weight packs Wt[n][k] = bf16(W[k][n]); also zeroes
// deg/cursor/xs (folded memsets; stream order covers the later consumers).
// ---------------------------------------------------------------------------
__global__ __launch_bounds__(128) void k_pack2(
    const float* __restrict__ We1, const float* __restrict__ We2,
    const float* __restrict__ Wc1, const float* __restrict__ Wn1,
    const float* __restrict__ Wn2,
    unsigned short* __restrict__ Wt_e1, unsigned short* __restrict__ Wt_e2,
    unsigned short* __restrict__ Wt_c1, unsigned short* __restrict__ Wt_n1,
    unsigned short* __restrict__ Wt_n2,
    int* __restrict__ deg, int* __restrict__ cursor, float* __restrict__ xs) {
    const int b = blockIdx.x;   // 0..255
    const int t = threadIdx.x;  // 0..127
    Wt_e1[b * 128 + t] = f2bf(We1[(size_t)((b >> 7) * 128 + t) * 128 + (b & 127)]);
    if (b < 128) {
        Wt_e2[b * 128 + t] = f2bf(We2[(size_t)t * 128 + b]);
        Wt_c1[b * 128 + t] = f2bf(Wc1[(size_t)t * 128 + b]);
        Wt_n2[b * 128 + t] = f2bf(Wn2[(size_t)t * 128 + b]);
        Wt_n1[b * 256 + t] = f2bf(Wn1[(size_t)t * 128 + b]);
        Wt_n1[b * 256 + 128 + t] = f2bf(Wn1[(size_t)(128 + t) * 128 + b]);
    }
    const int gid = b * 128 + t;                   // 0..32767
    for (int i = gid; i < N_NODES; i += 32768) { deg[i] = 0; cursor[i] = 0; }
    for (int i = gid; i < N_NODES * 4; i += 32768) xs[i] = 0.0f;
}

// ---------------------------------------------------------------------------
// k_pre (MFMA): Pc[node][0:128]=nf@We1a, Pc[node][128:256]=nf@We1b, bf16 out.
// Also zeroes this block's 32 hn rows (folded memset).
// ---------------------------------------------------------------------------
__global__ __launch_bounds__(256) void k_pre(
    const float* __restrict__ nf, const unsigned short* __restrict__ Wt_e1,
    unsigned short* __restrict__ Pc, float* __restrict__ hn) {
    __shared__ __align__(16) unsigned short sNF[32][136];
    const int t = threadIdx.x;
    const int node0 = blockIdx.x * 32;
    {
        float4* hz = (float4*)(hn + (size_t)node0 * 128);   // 1024 float4s
#pragma unroll
        for (int i = 0; i < 4; i++) hz[t + 256 * i] = (float4){0.f, 0.f, 0.f, 0.f};
    }
    {
        const int m = t >> 3, kc = (t & 7) * 16;
        const float* sp = &nf[(size_t)(node0 + m) * 128 + kc];
#pragma unroll
        for (int kk = 0; kk < 16; kk += 4) {
            const float4 v = *(const float4*)(sp + kk);
            sNF[m][kc + kk + 0] = f2bf(v.x);
            sNF[m][kc + kk + 1] = f2bf(v.y);
            sNF[m][kc + kk + 2] = f2bf(v.z);
            sNF[m][kc + kk + 3] = f2bf(v.w);
        }
    }
    __syncthreads();

    const int w = t >> 6, l = t & 63, c = l & 15, quad = l >> 4;
    const int n0 = w * 64;

    f32x4 acc[2][4];
#pragma unroll
    for (int mt = 0; mt < 2; mt++)
#pragma unroll
        for (int tile = 0; tile < 4; tile++) acc[mt][tile] = (f32x4){0.f, 0.f, 0.f, 0.f};

#pragma unroll
    for (int k0 = 0; k0 < 128; k0 += 32) {
        const short8 a0 = *(const short8*)&sNF[c][k0 + quad * 8];
        const short8 a1 = *(const short8*)&sNF[16 + c][k0 + quad * 8];
#pragma unroll
        for (int tile = 0; tile < 4; tile++) {
            const short8 b = *(const short8*)(Wt_e1 +
                ((size_t)(n0 + tile * 16 + c) << 7) + k0 + quad * 8);
            acc[0][tile] = __builtin_amdgcn_mfma_f32_16x16x32_bf16(a0, b, acc[0][tile], 0, 0, 0);
            acc[1][tile] = __builtin_amdgcn_mfma_f32_16x16x32_bf16(a1, b, acc[1][tile], 0, 0, 0);
        }
    }
#pragma unroll
    for (int mt = 0; mt < 2; mt++)
#pragma unroll
        for (int tile = 0; tile < 4; tile++) {
            const int col = n0 + tile * 16 + c;
#pragma unroll
            for (int r = 0; r < 4; r++) {
                const int row = mt * 16 + quad * 4 + r;
                Pc[(size_t)(node0 + row) * 256 + col] = f2bf(acc[mt][tile][r]);
            }
        }
}

// ---------------------------------------------------------------------------
// k_edge4: 64 CSR-permuted edges per 512-thread block (8 waves).
//   wave w: edge quarter h=w&3 (m0=h*16), col half H=w>>2 (n0=H*64).
//   h-scatter issued BEFORE GEMM2 so atomics drain under MFMA work.
// ---------------------------------------------------------------------------
__global__ __launch_bounds__(512) void k_edge4(
    const unsigned short* __restrict__ Pc, const float* __restrict__ coord,
    const int* __restrict__ src, const int* __restrict__ dst,
    const int* __restrict__ elist,
    const float* __restrict__ We1, const float* __restrict__ be1,
    const unsigned short* __restrict__ Wt_e2, const float* __restrict__ be2,
    const unsigned short* __restrict__ Wt_c1, const float* __restrict__ bc1,
    const float* __restrict__ Wc2,
    float* __restrict__ h_neigh, float* __restrict__ xs) {
    __shared__ __align__(16) unsigned short sT1[64][136];
    __shared__ __align__(16) unsigned short sT2[64][136];
    __shared__ float scoefp[8][16];
    __shared__ float sw[128], sb[128];
    __shared__ float sdist[64];
    __shared__ float sxd[64][3];
    __shared__ int ssrc[64];
    __shared__ int sdst[64];

    const int t = threadIdx.x;
    const int e0 = blockIdx.x * 64;

    if (t < 64) {
        const int eid = elist[e0 + t];
        const int s = src[eid], d = dst[eid];
        ssrc[t] = s; sdst[t] = d;
        const float dx = coord[3 * s + 0] - coord[3 * d + 0];
        const float dy = coord[3 * s + 1] - coord[3 * d + 1];
        const float dz = coord[3 * s + 2] - coord[3 * d + 2];
        const float dist = sqrtf(dx * dx + dy * dy + dz * dz);
        sdist[t] = dist;
        const float inv = 1.0f / (dist + 1e-7f);
        sxd[t][0] = dx * inv; sxd[t][1] = dy * inv; sxd[t][2] = dz * inv;
    } else if (t < 96) {
        ((float4*)sw)[t - 64] = ((const float4*)(We1 + 256 * 128))[t - 64];
    } else if (t < 128) {
        ((float4*)sb)[t - 96] = ((const float4*)be1)[t - 96];
    }
    __syncthreads();

    // t1 = silu(P1[s] + P2[d] + dist*We1[256] + be1), bf16, vector LDS writes
    {
        const int e = t >> 3;
        const int kc = (t & 7) * 16;
        const int s = ssrc[e], d = sdst[e];
        const float dist = sdist[e];
        const unsigned short* p1 = Pc + (size_t)s * 256 + kc;
        const unsigned short* p2 = Pc + (size_t)d * 256 + 128 + kc;
        const short8 a0 = *(const short8*)p1;
        const short8 a1 = *(const short8*)(p1 + 8);
        const short8 b0 = *(const short8*)p2;
        const short8 b1 = *(const short8*)(p2 + 8);
        short8 o0, o1;
#pragma unroll
        for (int kk = 0; kk < 8; kk++) {
            const float v = bf2f((unsigned short)a0[kk]) + bf2f((unsigned short)b0[kk])
                          + dist * sw[kc + kk] + sb[kc + kk];
            o0[kk] = (short)f2bf(silu(v));
        }
#pragma unroll
        for (int kk = 0; kk < 8; kk++) {
            const float v = bf2f((unsigned short)a1[kk]) + bf2f((unsigned short)b1[kk])
                          + dist * sw[kc + 8 + kk] + sb[kc + 8 + kk];
            o1[kk] = (short)f2bf(silu(v));
        }
        *(short8*)&sT1[e][kc] = o0;
        *(short8*)&sT1[e][kc + 8] = o1;
    }
    __syncthreads();

    const int w = t >> 6;
    const int l = t & 63;
    const int h = w & 3;      // edge quarter
    const int H = w >> 2;     // col half
    const int m0 = h * 16;
    const int n0 = H * 64;
    const int c = l & 15;
    const int quad = l >> 4;

    // ---- GEMM1: t2 = silu(t1 @ We2 + be2) ----
    {
        f32x4 acc[4];
#pragma unroll
        for (int tile = 0; tile < 4; tile++) acc[tile] = (f32x4){0.f, 0.f, 0.f, 0.f};
#pragma unroll
        for (int k0 = 0; k0 < 128; k0 += 32) {
            const short8 a = *(const short8*)&sT1[m0 + c][k0 + quad * 8];
#pragma unroll
            for (int tile = 0; tile < 4; tile++) {
                const short8 b = *(const short8*)(Wt_e2 +
                    ((size_t)(n0 + tile * 16 + c) << 7) + k0 + quad * 8);
                acc[tile] = __builtin_amdgcn_mfma_f32_16x16x32_bf16(a, b, acc[tile], 0, 0, 0);
            }
        }
#pragma unroll
        for (int tile = 0; tile < 4; tile++) {
            const int col = n0 + tile * 16 + c;
            const float bb = be2[col];
#pragma unroll
            for (int r = 0; r < 4; r++) {
                sT2[m0 + quad * 4 + r][col] = f2bf(silu(acc[tile][r] + bb));
            }
        }
    }
    __syncthreads();

    // ---- h-scatter first: atomics drain under GEMM2's compute ----
    {
        const int j = t & 127;
        const int q = t >> 7;
        const int eb = q * 16;
        float acc = bf2f(sT2[eb][j]);
        int prev = sdst[eb];
        for (int e2 = eb + 1; e2 < eb + 16; e2++) {
            const int de = sdst[e2];
            if (de != prev) {
                atomicAdd(&h_neigh[(size_t)prev * 128 + j], acc);
                acc = 0.0f;
                prev = de;
            }
            acc += bf2f(sT2[e2][j]);
        }
        atomicAdd(&h_neigh[(size_t)prev * 128 + j], acc);
    }

    // ---- GEMM2: coef = silu(t2 @ Wc1 + bc1) . Wc2 ----
    {
        f32x4 acc[4];
#pragma unroll
        for (int tile = 0; tile < 4; tile++) acc[tile] = (f32x4){0.f, 0.f, 0.f, 0.f};
#pragma unroll
        for (int k0 = 0; k0 < 128; k0 += 32) {
            const short8 a = *(const short8*)&sT2[m0 + c][k0 + quad * 8];
#pragma unroll
            for (int tile = 0; tile < 4; tile++) {
                const short8 b = *(const short8*)(Wt_c1 +
                    ((size_t)(n0 + tile * 16 + c) << 7) + k0 + quad * 8);
                acc[tile] = __builtin_amdgcn_mfma_f32_16x16x32_bf16(a, b, acc[tile], 0, 0, 0);
            }
        }
        float part[4] = {0.f, 0.f, 0.f, 0.f};
#pragma unroll
        for (int tile = 0; tile < 4; tile++) {
            const int col = n0 + tile * 16 + c;
            const float bc = bc1[col];
            const float wc = Wc2[col];
#pragma unroll
            for (int r = 0; r < 4; r++) part[r] += silu(acc[tile][r] + bc) * wc;
        }
#pragma unroll
        for (int off = 1; off < 16; off <<= 1) {
#pragma unroll
            for (int r = 0; r < 4; r++) part[r] += __shfl_xor(part[r], off, 64);
        }
        if (c == 0) {
#pragma unroll
            for (int r = 0; r < 4; r++) scoefp[w][quad * 4 + r] = part[r];
        }
    }
    __syncthreads();

    // ---- x-scatter (12 threads; coef = colhalf0 + colhalf1 partials) ----
    if (t < 12) {
        const int q = t / 3, cc = t - q * 3;
        const int eb = q * 16;
        float coef = scoefp[eb >> 4][eb & 15] + scoefp[(eb >> 4) + 4][eb & 15];
        float acc = coef * sxd[eb][cc];
        int prev = sdst[eb];
        for (int e2 = eb + 1; e2 < eb + 16; e2++) {
            const int de = sdst[e2];
            if (de != prev) {
                atomicAdd(&xs[(size_t)prev * 4 + cc], acc);
                acc = 0.0f;
                prev = de;
            }
            coef = scoefp[e2 >> 4][e2 & 15] + scoefp[(e2 >> 4) + 4][e2 & 15];
            acc += coef * sxd[e2][cc];
        }
        atomicAdd(&xs[(size_t)prev * 4 + cc], acc);
    }
}

// ---------------------------------------------------------------------------
// k_node (MFMA): h = silu([nf|hn] @ Wn1 + bn1) @ Wn2 + bn2 ; x = coord+xs/cnt
// ---------------------------------------------------------------------------
__global__ __launch_bounds__(256) void k_node(
    const float* __restrict__ nf, const float* __restrict__ coord,
    const float* __restrict__ hn, const float* __restrict__ xs,
    const int* __restrict__ row_start,
    const unsigned short* __restrict__ Wt_n1, const float* __restrict__ bn1,
    const unsigned short* __restrict__ Wt_n2, const float* __restrict__ bn2,
    float* __restrict__ out_h, float* __restrict__ out_x) {
    __shared__ __align__(16) unsigned short sAB[32][264];
    __shared__ __align__(16) unsigned short sH[32][136];
    const int t = threadIdx.x;
    const int node0 = blockIdx.x * 32;
    {
        const int m = t >> 3, kc = (t & 7) * 32;
        const float* base = (kc < 128) ? &nf[(size_t)(node0 + m) * 128 + kc]
                                       : &hn[(size_t)(node0 + m) * 128 + (kc - 128)];
#pragma unroll
        for (int kk = 0; kk < 32; kk += 4) {
            const float4 v = *(const float4*)(base + kk);
            sAB[m][kc + kk + 0] = f2bf(v.x);
            sAB[m][kc + kk + 1] = f2bf(v.y);
            sAB[m][kc + kk + 2] = f2bf(v.z);
            sAB[m][kc + kk + 3] = f2bf(v.w);
        }
    }
    if (t < 96) {
        const int m = t / 3, cc = t - m * 3;
        const int i = node0 + m;
        const float cnt = (float)(row_start[i + 1] - row_start[i]);
        out_x[(size_t)i * 3 + cc] =
            coord[(size_t)i * 3 + cc] + xs[(size_t)i * 4 + cc] / fmaxf(cnt, 1.0f);
    }
    __syncthreads();

    const int w = t >> 6, l = t & 63, c = l & 15, quad = l >> 4;
    const int n0 = w * 32;

    // GEMM1: M=32, K=256, N=128
    {
        f32x4 acc[2][2];
#pragma unroll
        for (int mt = 0; mt < 2; mt++)
#pragma unroll
            for (int tile = 0; tile < 2; tile++) acc[mt][tile] = (f32x4){0.f, 0.f, 0.f, 0.f};
#pragma unroll
        for (int k0 = 0; k0 < 256; k0 += 32) {
            const short8 a0 = *(const short8*)&sAB[c][k0 + quad * 8];
            const short8 a1 = *(const short8*)&sAB[16 + c][k0 + quad * 8];
#pragma unroll
            for (int tile = 0; tile < 2; tile++) {
                const short8 b = *(const short8*)(Wt_n1 +
                    ((size_t)(n0 + tile * 16 + c) << 8) + k0 + quad * 8);
                acc[0][tile] = __builtin_amdgcn_mfma_f32_16x16x32_bf16(a0, b, acc[0][tile], 0, 0, 0);
                acc[1][tile] = __builtin_amdgcn_mfma_f32_16x16x32_bf16(a1, b, acc[1][tile], 0, 0, 0);
            }
        }
#pragma unroll
        for (int mt = 0; mt < 2; mt++)
#pragma unroll
            for (int tile = 0; tile < 2; tile++) {
                const int col = n0 + tile * 16 + c;
                const float bb = bn1[col];
#pragma unroll
                for (int r = 0; r < 4; r++) {
                    sH[mt * 16 + quad * 4 + r][col] = f2bf(silu(acc[mt][tile][r] + bb));
                }
            }
    }
    __syncthreads();

    // GEMM2: M=32, K=128, N=128
    {
        f32x4 acc[2][2];
#pragma unroll
        for (int mt = 0; mt < 2; mt++)
#pragma unroll
            for (int tile = 0; tile < 2; tile++) acc[mt][tile] = (f32x4){0.f, 0.f, 0.f, 0.f};
#pragma unroll
        for (int k0 = 0; k0 < 128; k0 += 32) {
            const short8 a0 = *(const short8*)&sH[c][k0 + quad * 8];
            const short8 a1 = *(const short8*)&sH[16 + c][k0 + quad * 8];
#pragma unroll
            for (int tile = 0; tile < 2; tile++) {
                const short8 b = *(const short8*)(Wt_n2 +
                    ((size_t)(n0 + tile * 16 + c) << 7) + k0 + quad * 8);
                acc[0][tile] = __builtin_amdgcn_mfma_f32_16x16x32_bf16(a0, b, acc[0][tile], 0, 0, 0);
                acc[1][tile] = __builtin_amdgcn_mfma_f32_16x16x32_bf16(a1, b, acc[1][tile], 0, 0, 0);
            }
        }
#pragma unroll
        for (int mt = 0; mt < 2; mt++)
#pragma unroll
            for (int tile = 0; tile < 2; tile++) {
                const int col = n0 + tile * 16 + c;
                const float bb = bn2[col];
#pragma unroll
                for (int r = 0; r < 4; r++) {
                    const int row = mt * 16 + quad * 4 + r;
                    out_h[(size_t)(node0 + row) * 128 + col] = acc[mt][tile][r] + bb;
                }
            }
    }
}

// ---------------------------------------------------------------------------
extern "C" void kernel_launch(void* const* d_in, const int* in_sizes, int n_in,
                              void* d_out, int out_size, void* d_ws, size_t ws_size,
                              hipStream_t stream) {
    const float* nf    = (const float*)d_in[0];
    const float* coord = (const float*)d_in[1];
    const int*   src   = (const int*)d_in[2];
    const int*   dst   = (const int*)d_in[3];
    const float* We1   = (const float*)d_in[4];
    const float* be1   = (const float*)d_in[5];
    const float* We2   = (const float*)d_in[6];
    const float* be2   = (const float*)d_in[7];
    const float* Wn1   = (const float*)d_in[8];
    const float* bn1   = (const float*)d_in[9];
    const float* Wn2   = (const float*)d_in[10];
    const float* bn2   = (const float*)d_in[11];
    const float* Wc1   = (const float*)d_in[12];
    const float* bc1   = (const float*)d_in[13];
    const float* Wc2   = (const float*)d_in[14];

    unsigned short* Pc = (unsigned short*)d_ws;            // N*256 bf16
    float* hn = (float*)(Pc + (size_t)N_NODES * 256);      // N*128 f32
    float* xs = hn + (size_t)N_NODES * 128;                // N*4
    int* deg       = (int*)(xs + (size_t)N_NODES * 4);     // N
    int* row_start = deg + N_NODES;                        // N+1
    int* cursor    = row_start + N_NODES + 1;              // N
    int* elist     = cursor + N_NODES;                     // E
    unsigned short* Wt_e1 = (unsigned short*)
        (((uintptr_t)(elist + N_EDGES) + 255) & ~(uintptr_t)255);  // 256*128
    unsigned short* Wt_e2 = Wt_e1 + 256 * 128;                     // 128*128
    unsigned short* Wt_c1 = Wt_e2 + 128 * 128;                     // 128*128
    unsigned short* Wt_n1 = Wt_c1 + 128 * 128;                     // 128*256
    unsigned short* Wt_n2 = Wt_n1 + 128 * 256;                     // 128*128

    float* out_h = (float*)d_out;                          // N*128
    float* out_x = out_h + (size_t)N_NODES * 128;          // N*3

    k_pack2<<<256, 128, 0, stream>>>(We1, We2, Wc1, Wn1, Wn2,
                                     Wt_e1, Wt_e2, Wt_c1, Wt_n1, Wt_n2,
                                     deg, cursor, xs);
    k_count<<<(N_EDGES + 255) / 256, 256, 0, stream>>>(dst, deg);
    k_scan<<<1, 1024, 0, stream>>>(deg, row_start);
    k_fill<<<(N_EDGES + 255) / 256, 256, 0, stream>>>(dst, row_start, cursor, elist);
    k_pre<<<N_NODES / 32, 256, 0, stream>>>(nf, Wt_e1, Pc, hn);
    k_edge4<<<N_EDGES / 64, 512, 0, stream>>>(Pc, coord, src, dst, elist,
                                              We1, be1, Wt_e2, be2, Wt_c1, bc1,
                                              Wc2, hn, xs);
    k_node<<<N_NODES / 32, 256, 0, stream>>>(nf, coord, hn, xs, row_start,
                                             Wt_n1, bn1, Wt_n2, bn2, out_h, out_x);
}